// Round 1
// baseline (2843.130 us; speedup 1.0000x reference)
//
#include <hip/hip_runtime.h>
#include <hip/hip_bf16.h>
#include <math.h>

#define T_STEPS 12
#define NNODES  20000
#define NEDGES  320000
#define FIN     128
#define HG      256
#define RS_STRIDE 20032   // rowstart stride per t (>= NNODES+1)

// ---------------- CSR build (batched over all 12 timesteps) ----------------

__global__ void hist_kernel(const int* __restrict__ edges, int* __restrict__ hist) {
    int idx = blockIdx.x * blockDim.x + threadIdx.x;
    if (idx >= T_STEPS * NEDGES) return;
    int t = idx / NEDGES, e = idx - t * NEDGES;
    int d = edges[t * 2 * NEDGES + NEDGES + e];
    atomicAdd(&hist[t * NNODES + d], 1);
}

// One block per timestep: exclusive scan of hist -> rowstart, dinv = rsqrt(deg+1),
// and re-zero hist so it can be reused as the fill cursor.
__global__ void __launch_bounds__(1024) scan_kernel(int* __restrict__ hist,
        int* __restrict__ rowstart, float* __restrict__ dinv) {
    int t = blockIdx.x;
    int tid = threadIdx.x;
    __shared__ int buf[1024];
    __shared__ int carry_s;
    if (tid == 0) carry_s = 0;
    __syncthreads();
    for (int base = 0; base < NNODES; base += 1024) {
        int i = base + tid;
        int v = (i < NNODES) ? hist[t * NNODES + i] : 0;
        buf[tid] = v;
        __syncthreads();
        for (int off = 1; off < 1024; off <<= 1) {
            int add = (tid >= off) ? buf[tid - off] : 0;
            __syncthreads();
            buf[tid] += add;
            __syncthreads();
        }
        int incl = buf[tid];
        int excl = incl - v + carry_s;
        if (i < NNODES) {
            rowstart[t * RS_STRIDE + i] = excl;
            dinv[t * NNODES + i] = rsqrtf((float)(v + 1));  // deg = in-degree + self-loop
            hist[t * NNODES + i] = 0;                       // cursor for fill
        }
        __syncthreads();
        if (tid == 1023) carry_s += incl;
        __syncthreads();
    }
    if (tid == 0) rowstart[t * RS_STRIDE + NNODES] = carry_s;
}

__global__ void fill_kernel(const int* __restrict__ edges, const int* __restrict__ rowstart,
        int* __restrict__ cursor, int* __restrict__ col) {
    int idx = blockIdx.x * blockDim.x + threadIdx.x;
    if (idx >= T_STEPS * NEDGES) return;
    int t = idx / NEDGES, e = idx - t * NEDGES;
    int s = edges[t * 2 * NEDGES + e];
    int d = edges[t * 2 * NEDGES + NEDGES + e];
    int pos = rowstart[t * RS_STRIDE + d] + atomicAdd(&cursor[t * NNODES + d], 1);
    col[t * NEDGES + pos] = s;
}

// ---------------- pull-based sym-norm aggregation ----------------
// out[d] = dinv[d] * ( sum_{s->d} dinv[s]*x[s] + dinv[d]*x[d] )
// one wave (64 lanes) per node

__global__ void __launch_bounds__(256) agg128(const float* __restrict__ xin,
        const int* __restrict__ rowstart, const int* __restrict__ col,
        const float* __restrict__ dinv, float* __restrict__ out) {
    int node = (blockIdx.x << 2) + (threadIdx.x >> 6);
    int lane = threadIdx.x & 63;
    float dn = dinv[node];
    float2 v = *(const float2*)&xin[(size_t)node * FIN + (lane << 1)];
    float ax = dn * v.x, ay = dn * v.y;
    int s0 = rowstart[node], s1 = rowstart[node + 1];
    for (int e = s0; e < s1; ++e) {
        int s = col[e];
        float ds = dinv[s];
        float2 u = *(const float2*)&xin[(size_t)s * FIN + (lane << 1)];
        ax += ds * u.x; ay += ds * u.y;
    }
    float2 o; o.x = dn * ax; o.y = dn * ay;
    *(float2*)&out[(size_t)node * FIN + (lane << 1)] = o;
}

__global__ void __launch_bounds__(256) agg256(const float* __restrict__ xin,
        const int* __restrict__ rowstart, const int* __restrict__ col,
        const float* __restrict__ dinv, float* __restrict__ out) {
    int node = (blockIdx.x << 2) + (threadIdx.x >> 6);
    int lane = threadIdx.x & 63;
    float dn = dinv[node];
    float4 v = *(const float4*)&xin[(size_t)node * HG + (lane << 2)];
    float a0 = dn * v.x, a1 = dn * v.y, a2 = dn * v.z, a3 = dn * v.w;
    int s0 = rowstart[node], s1 = rowstart[node + 1];
    for (int e = s0; e < s1; ++e) {
        int s = col[e];
        float ds = dinv[s];
        float4 u = *(const float4*)&xin[(size_t)s * HG + (lane << 2)];
        a0 += ds * u.x; a1 += ds * u.y; a2 += ds * u.z; a3 += ds * u.w;
    }
    float4 o; o.x = dn * a0; o.y = dn * a1; o.z = dn * a2; o.w = dn * a3;
    *(float4*)&out[(size_t)node * HG + (lane << 2)] = o;
}

// ---------------- fp32 GEMM, C = relu(A@B + bias) ----------------
// A [M,K] row-major, B [K,256] row-major. 64x64 tile, BK=16, 4x4 per thread.
// POOL=true: instead of storing C, accumulate column sums into pool[256] (atomic).

template <bool POOL>
__global__ void __launch_bounds__(256) gemm_relu(const float* __restrict__ A,
        const float* __restrict__ B, const float* __restrict__ bias,
        float* __restrict__ C, float* __restrict__ pool, int M, int K) {
    __shared__ float As[16][68];
    __shared__ float Bs[16][68];
    __shared__ float csum[64];
    int tid = threadIdx.x;
    int bm = blockIdx.x * 64, bn = blockIdx.y * 64;
    int tx = tid & 15, ty = tid >> 4;
    int lr = tid >> 2, lk = (tid & 3) << 2;       // A loader: row lr, k-quad lk
    int lk2 = tid >> 4, ln = (tid & 15) << 2;     // B loader: k lk2, n-quad ln
    float acc[4][4] = {};
    for (int k0 = 0; k0 < K; k0 += 16) {
        float4 av = make_float4(0.f, 0.f, 0.f, 0.f);
        if (bm + lr < M) av = *(const float4*)&A[(size_t)(bm + lr) * K + k0 + lk];
        float4 bv = *(const float4*)&B[(size_t)(k0 + lk2) * HG + bn + ln];
        As[lk + 0][lr] = av.x; As[lk + 1][lr] = av.y;
        As[lk + 2][lr] = av.z; As[lk + 3][lr] = av.w;
        *(float4*)&Bs[lk2][ln] = bv;
        __syncthreads();
#pragma unroll
        for (int kk = 0; kk < 16; ++kk) {
            const float4 a = *(const float4*)&As[kk][ty << 2];
            const float4 b = *(const float4*)&Bs[kk][tx << 2];
            acc[0][0] += a.x * b.x; acc[0][1] += a.x * b.y; acc[0][2] += a.x * b.z; acc[0][3] += a.x * b.w;
            acc[1][0] += a.y * b.x; acc[1][1] += a.y * b.y; acc[1][2] += a.y * b.z; acc[1][3] += a.y * b.w;
            acc[2][0] += a.z * b.x; acc[2][1] += a.z * b.y; acc[2][2] += a.z * b.z; acc[2][3] += a.z * b.w;
            acc[3][0] += a.w * b.x; acc[3][1] += a.w * b.y; acc[3][2] += a.w * b.z; acc[3][3] += a.w * b.w;
        }
        __syncthreads();
    }
    float bj[4];
#pragma unroll
    for (int j = 0; j < 4; ++j) bj[j] = bias[bn + (tx << 2) + j];
    if (!POOL) {
#pragma unroll
        for (int i = 0; i < 4; ++i) {
            int r = bm + (ty << 2) + i;
            if (r < M) {
                float4 o;
                o.x = fmaxf(acc[i][0] + bj[0], 0.f);
                o.y = fmaxf(acc[i][1] + bj[1], 0.f);
                o.z = fmaxf(acc[i][2] + bj[2], 0.f);
                o.w = fmaxf(acc[i][3] + bj[3], 0.f);
                *(float4*)&C[(size_t)r * HG + bn + (tx << 2)] = o;
            }
        }
    } else {
        if (tid < 64) csum[tid] = 0.f;
        __syncthreads();
#pragma unroll
        for (int i = 0; i < 4; ++i) {
            int r = bm + (ty << 2) + i;
            if (r < M) {
#pragma unroll
                for (int j = 0; j < 4; ++j)
                    atomicAdd(&csum[(tx << 2) + j], fmaxf(acc[i][j] + bj[j], 0.f));
            }
        }
        __syncthreads();
        if (tid < 64) atomicAdd(&pool[bn + tid], csum[tid]);
    }
}

// ---------------- weight transposes for the LSTM (coalesced reads) ----------------
// in: [1024][256] row-major -> out: [256][1024]
__global__ void transpose4(const float* __restrict__ a, const float* __restrict__ b,
        const float* __restrict__ cc, const float* __restrict__ d, float* __restrict__ WT) {
    int idx = blockIdx.x * blockDim.x + threadIdx.x;
    int m = idx >> 18;
    int r = idx & 262143;
    const float* src = (m == 0) ? a : (m == 1) ? b : (m == 2) ? cc : d;
    int g = r >> 8, k = r & 255;
    WT[(m << 18) + (k << 10) + g] = src[r];
}

// ---------------- 2-layer LSTM + final linear, single block ----------------

__device__ __forceinline__ float sigm(float x) { return 1.f / (1.f + expf(-x)); }

__global__ void __launch_bounds__(1024) lstm_kernel(const float* __restrict__ pooled,
        const float* __restrict__ WT,
        const float* __restrict__ bih0, const float* __restrict__ bhh0,
        const float* __restrict__ bih1, const float* __restrict__ bhh1,
        const float* __restrict__ Wlin, const float* __restrict__ blin,
        float* __restrict__ out) {
    __shared__ float xs[T_STEPS][HG];
    __shared__ float hseq[T_STEPS][HG];
    __shared__ float h[256], c[256];
    __shared__ float gates[1024];
    int tid = threadIdx.x;
    for (int i = tid; i < T_STEPS * HG; i += 1024)
        ((float*)xs)[i] = pooled[i] * (1.0f / (float)NNODES);   // mean pool divide
    __syncthreads();
    for (int layer = 0; layer < 2; ++layer) {
        const float* WihT = WT + layer * 524288;   // [256][1024]
        const float* WhhT = WihT + 262144;
        float bias = layer ? (bih1[tid] + bhh1[tid]) : (bih0[tid] + bhh0[tid]);
        const float (*in)[HG] = layer ? hseq : xs;
        // input projections for all 12 steps, weights reused across t (registers)
        float pre[T_STEPS];
#pragma unroll
        for (int t = 0; t < T_STEPS; ++t) pre[t] = 0.f;
        for (int k = 0; k < 256; ++k) {
            float w = WihT[k * 1024 + tid];
#pragma unroll
            for (int t = 0; t < T_STEPS; ++t) pre[t] += in[t][k] * w;
        }
        if (tid < 256) { h[tid] = 0.f; c[tid] = 0.f; }
        __syncthreads();
#pragma unroll
        for (int t = 0; t < T_STEPS; ++t) {
            float p = pre[t] + bias;
            for (int k = 0; k < 256; ++k) p += h[k] * WhhT[k * 1024 + tid];
            gates[tid] = p;
            __syncthreads();
            if (tid < 256) {
                float ig = sigm(gates[tid]);
                float fg = sigm(gates[256 + tid]);
                float gg = tanhf(gates[512 + tid]);
                float og = sigm(gates[768 + tid]);
                float cn = fg * c[tid] + ig * gg;
                c[tid] = cn;
                float hn = og * tanhf(cn);
                h[tid] = hn;
                hseq[t][tid] = hn;
            }
            __syncthreads();
        }
    }
    if (tid < 8) {
        float s = blin[tid];
        for (int k = 0; k < 256; ++k) s += h[k] * Wlin[tid * 256 + k];
        out[tid] = s;
    }
}

// ---------------- orchestration ----------------

extern "C" void kernel_launch(void* const* d_in, const int* in_sizes, int n_in,
                              void* d_out, int out_size, void* d_ws, size_t ws_size,
                              hipStream_t stream) {
    const float* x    = (const float*)d_in[0];
    const int*   edges= (const int*)d_in[1];
    const float* W1   = (const float*)d_in[3];
    const float* b1   = (const float*)d_in[4];
    const float* W2   = (const float*)d_in[5];
    const float* b2   = (const float*)d_in[6];
    const float* Wih0 = (const float*)d_in[7];
    const float* Whh0 = (const float*)d_in[8];
    const float* bih0 = (const float*)d_in[9];
    const float* bhh0 = (const float*)d_in[10];
    const float* Wih1 = (const float*)d_in[11];
    const float* Whh1 = (const float*)d_in[12];
    const float* bih1 = (const float*)d_in[13];
    const float* bhh1 = (const float*)d_in[14];
    const float* Wlin = (const float*)d_in[15];
    const float* blin = (const float*)d_in[16];

    char* p = (char*)d_ws;
    auto alloc = [&](size_t bytes) -> char* {
        char* q = p; p += (bytes + 255) & ~(size_t)255; return q;
    };
    int*   hist     = (int*)  alloc(sizeof(int)   * T_STEPS * NNODES);
    int*   rowstart = (int*)  alloc(sizeof(int)   * T_STEPS * RS_STRIDE);
    float* dinv     = (float*)alloc(sizeof(float) * T_STEPS * NNODES);
    int*   col      = (int*)  alloc(sizeof(int)   * T_STEPS * NEDGES);
    float* agg1     = (float*)alloc(sizeof(float) * (size_t)NNODES * FIN);
    float* h1b      = (float*)alloc(sizeof(float) * (size_t)NNODES * HG);
    float* agg2     = (float*)alloc(sizeof(float) * (size_t)NNODES * HG);
    float* pooled   = (float*)alloc(sizeof(float) * T_STEPS * HG);
    float* WT       = (float*)alloc(sizeof(float) * 4 * 262144);
    (void)ws_size; (void)in_sizes; (void)n_in; (void)out_size;

    hipMemsetAsync(hist, 0, sizeof(int) * T_STEPS * NNODES, stream);
    hipMemsetAsync(pooled, 0, sizeof(float) * T_STEPS * HG, stream);

    int tot = T_STEPS * NEDGES;
    hist_kernel<<<(tot + 255) / 256, 256, 0, stream>>>(edges, hist);
    scan_kernel<<<T_STEPS, 1024, 0, stream>>>(hist, rowstart, dinv);
    fill_kernel<<<(tot + 255) / 256, 256, 0, stream>>>(edges, rowstart, hist, col);
    transpose4<<<4096, 256, 0, stream>>>(Wih0, Whh0, Wih1, Whh1, WT);

    for (int t = 0; t < T_STEPS; ++t) {
        agg128<<<NNODES / 4, 256, 0, stream>>>(x + (size_t)t * NNODES * FIN,
                rowstart + t * RS_STRIDE, col + (size_t)t * NEDGES, dinv + t * NNODES, agg1);
        gemm_relu<false><<<dim3(313, 4), 256, 0, stream>>>(agg1, W1, b1, h1b, nullptr, NNODES, FIN);
        agg256<<<NNODES / 4, 256, 0, stream>>>(h1b,
                rowstart + t * RS_STRIDE, col + (size_t)t * NEDGES, dinv + t * NNODES, agg2);
        gemm_relu<true><<<dim3(313, 4), 256, 0, stream>>>(agg2, W2, b2, nullptr,
                pooled + t * HG, NNODES, HG);
    }
    lstm_kernel<<<1, 1024, 0, stream>>>(pooled, WT, bih0, bhh0, bih1, bhh1, Wlin, blin,
                                        (float*)d_out);
}

// Round 2
// 2361.292 us; speedup vs baseline: 1.2041x; 1.2041x over previous
//
#include <hip/hip_runtime.h>
#include <hip/hip_bf16.h>
#include <math.h>

#define T_STEPS 12
#define NNODES  20000
#define NEDGES  320000
#define MPAD    20032
#define FIN     128
#define HG      256
#define RS_STRIDE 20032

typedef unsigned short u16;
typedef unsigned int   u32;
using bf16x8 = __attribute__((ext_vector_type(8))) short;
using f32x4  = __attribute__((ext_vector_type(4))) float;

__device__ __forceinline__ float bf2f(u16 u) {
    union { u32 i; float f; } v; v.i = ((u32)u) << 16; return v.f;
}
__device__ __forceinline__ u16 f2bf(float f) {
    union { float f; u32 i; } v; v.f = f;
    u32 r = v.i + 0x7fffu + ((v.i >> 16) & 1u);
    return (u16)(r >> 16);
}
__device__ __forceinline__ void gload16(const void* g, void* l) {
    __builtin_amdgcn_global_load_lds(
        (const __attribute__((address_space(1))) u32*)g,
        (__attribute__((address_space(3))) u32*)l, 16, 0, 0);
}
__device__ __forceinline__ float sigm(float x) { return 1.f / (1.f + expf(-x)); }

// ---------------- CSR build (unchanged, verified) ----------------

__global__ void hist_kernel(const int* __restrict__ edges, int* __restrict__ hist) {
    int idx = blockIdx.x * blockDim.x + threadIdx.x;
    if (idx >= T_STEPS * NEDGES) return;
    int t = idx / NEDGES, e = idx - t * NEDGES;
    int d = edges[t * 2 * NEDGES + NEDGES + e];
    atomicAdd(&hist[t * NNODES + d], 1);
}

__global__ void __launch_bounds__(1024) scan_kernel(int* __restrict__ hist,
        int* __restrict__ rowstart, float* __restrict__ dinv) {
    int t = blockIdx.x;
    int tid = threadIdx.x;
    __shared__ int buf[1024];
    __shared__ int carry_s;
    if (tid == 0) carry_s = 0;
    __syncthreads();
    for (int base = 0; base < NNODES; base += 1024) {
        int i = base + tid;
        int v = (i < NNODES) ? hist[t * NNODES + i] : 0;
        buf[tid] = v;
        __syncthreads();
        for (int off = 1; off < 1024; off <<= 1) {
            int add = (tid >= off) ? buf[tid - off] : 0;
            __syncthreads();
            buf[tid] += add;
            __syncthreads();
        }
        int incl = buf[tid];
        int excl = incl - v + carry_s;
        if (i < NNODES) {
            rowstart[t * RS_STRIDE + i] = excl;
            dinv[t * NNODES + i] = rsqrtf((float)(v + 1));
            hist[t * NNODES + i] = 0;
        }
        __syncthreads();
        if (tid == 1023) carry_s += incl;
        __syncthreads();
    }
    if (tid == 0) rowstart[t * RS_STRIDE + NNODES] = carry_s;
}

__global__ void fill_kernel(const int* __restrict__ edges, const int* __restrict__ rowstart,
        int* __restrict__ cursor, int* __restrict__ col) {
    int idx = blockIdx.x * blockDim.x + threadIdx.x;
    if (idx >= T_STEPS * NEDGES) return;
    int t = idx / NEDGES, e = idx - t * NEDGES;
    int s = edges[t * 2 * NEDGES + e];
    int d = edges[t * 2 * NEDGES + NEDGES + e];
    int pos = rowstart[t * RS_STRIDE + d] + atomicAdd(&cursor[t * NNODES + d], 1);
    col[t * NEDGES + pos] = s;
}

// ---------------- weight transpose+convert: W [K][256] -> Wt [256][K] bf16 ----------------

__global__ void convw_kernel(const float* __restrict__ W, u16* __restrict__ Wt, int K) {
    int idx = blockIdx.x * blockDim.x + threadIdx.x;
    int n = idx / K, k = idx - n * K;
    Wt[idx] = f2bf(W[k * HG + n]);
}

// ---------------- pull aggregation ----------------
// out[d] = dinv[d] * ( sum_{s->d} dinv[s]*x[s] + dinv[d]*x[d] ), one wave per node

__global__ void __launch_bounds__(256) agg128(const float* __restrict__ xin,
        const int* __restrict__ rowstart, const int* __restrict__ col,
        const float* __restrict__ dinv, u16* __restrict__ out) {
    int node = (blockIdx.x << 2) + (threadIdx.x >> 6);
    int lane = threadIdx.x & 63;
    float dn = dinv[node];
    float2 v = *(const float2*)&xin[(size_t)node * FIN + (lane << 1)];
    float ax = dn * v.x, ay = dn * v.y;
    int s0 = rowstart[node], s1 = rowstart[node + 1];
    for (int e = s0; e < s1; ++e) {
        int s = col[e];
        float ds = dinv[s];
        float2 u = *(const float2*)&xin[(size_t)s * FIN + (lane << 1)];
        ax += ds * u.x; ay += ds * u.y;
    }
    u32 packed = (u32)f2bf(dn * ax) | ((u32)f2bf(dn * ay) << 16);
    *(u32*)&out[(size_t)node * FIN + (lane << 1)] = packed;
}

__global__ void __launch_bounds__(256) agg256(const u16* __restrict__ xin,
        const int* __restrict__ rowstart, const int* __restrict__ col,
        const float* __restrict__ dinv, u16* __restrict__ out) {
    int node = (blockIdx.x << 2) + (threadIdx.x >> 6);
    int lane = threadIdx.x & 63;
    float dn = dinv[node];
    ushort4 v = *(const ushort4*)&xin[(size_t)node * HG + (lane << 2)];
    float a0 = dn * bf2f(v.x), a1 = dn * bf2f(v.y), a2 = dn * bf2f(v.z), a3 = dn * bf2f(v.w);
    int s0 = rowstart[node], s1 = rowstart[node + 1];
    for (int e = s0; e < s1; ++e) {
        int s = col[e];
        float ds = dinv[s];
        ushort4 u = *(const ushort4*)&xin[(size_t)s * HG + (lane << 2)];
        a0 += ds * bf2f(u.x); a1 += ds * bf2f(u.y); a2 += ds * bf2f(u.z); a3 += ds * bf2f(u.w);
    }
    ushort4 o;
    o.x = f2bf(dn * a0); o.y = f2bf(dn * a1); o.z = f2bf(dn * a2); o.w = f2bf(dn * a3);
    *(ushort4*)&out[(size_t)node * HG + (lane << 2)] = o;
}

// ---------------- bf16 MFMA GEMM: C = relu(A @ Bt^T + bias) ----------------
// A [MPAD][K] bf16 row-major (rows >= NNODES are zero), Bt [256][K] bf16 (Bt[n][k]=W[k][n]).
// 64x64 tile, BK=64, 4 waves (2x2), each wave 32x32 via 2x2 mfma_16x16x32 frags.
// LDS slot-swizzle: row r slot s holds k-chunk (s ^ (r&7)) -> 2-way banks (free).
// POOL: accumulate relu column sums into pool[256] instead of storing C.

template <int K, bool POOL>
__global__ __launch_bounds__(256) void gemm_bf16(
        const u16* __restrict__ A, const u16* __restrict__ Bt,
        const float* __restrict__ bias,
        u16* __restrict__ C, float* __restrict__ pool) {
    __shared__ u16 As[64 * 64];
    __shared__ u16 Bs[64 * 64];
    __shared__ float csum[64];
    int tid = threadIdx.x;
    int bm = blockIdx.x * 64, bn = blockIdx.y * 64;
    int t8 = tid >> 3, sl = tid & 7;
    int lane = tid & 63, wid = tid >> 6;
    int wr = wid >> 1, wc = wid & 1;
    int r0 = lane & 15, gq = lane >> 4;

    f32x4 acc[2][2] = {};

    for (int k0 = 0; k0 < K; k0 += 64) {
#pragma unroll
        for (int i = 0; i < 2; ++i) {
            int r = i * 32 + t8;
            int ch = sl ^ (r & 7);
            gload16(A  + (size_t)(bm + r) * K + k0 + ch * 8, &As[i * 2048 + tid * 8]);
            gload16(Bt + (size_t)(bn + r) * K + k0 + ch * 8, &Bs[i * 2048 + tid * 8]);
        }
        __syncthreads();
#pragma unroll
        for (int kk = 0; kk < 2; ++kk) {
            bf16x8 a[2], b[2];
#pragma unroll
            for (int mi = 0; mi < 2; ++mi) {
                int R = wr * 32 + mi * 16 + r0;
                int s = (kk * 4 + gq) ^ (R & 7);
                a[mi] = *(const bf16x8*)&As[R * 64 + s * 8];
            }
#pragma unroll
            for (int ni = 0; ni < 2; ++ni) {
                int R = wc * 32 + ni * 16 + r0;
                int s = (kk * 4 + gq) ^ (R & 7);
                b[ni] = *(const bf16x8*)&Bs[R * 64 + s * 8];
            }
#pragma unroll
            for (int mi = 0; mi < 2; ++mi)
#pragma unroll
                for (int ni = 0; ni < 2; ++ni)
                    acc[mi][ni] = __builtin_amdgcn_mfma_f32_16x16x32_bf16(
                        a[mi], b[ni], acc[mi][ni], 0, 0, 0);
        }
        __syncthreads();
    }

    if (!POOL) {
#pragma unroll
        for (int ni = 0; ni < 2; ++ni) {
            int colg = bn + wc * 32 + ni * 16 + r0;
            float b = bias[colg];
#pragma unroll
            for (int mi = 0; mi < 2; ++mi) {
                int rbase = bm + wr * 32 + mi * 16 + gq * 4;
#pragma unroll
                for (int q = 0; q < 4; ++q) {
                    int row = rbase + q;
                    if (row < NNODES)
                        C[(size_t)row * HG + colg] = f2bf(fmaxf(acc[mi][ni][q] + b, 0.f));
                }
            }
        }
    } else {
        if (tid < 64) csum[tid] = 0.f;
        __syncthreads();
#pragma unroll
        for (int ni = 0; ni < 2; ++ni) {
            int lcol = wc * 32 + ni * 16 + r0;
            float b = bias[bn + lcol];
            float s = 0.f;
#pragma unroll
            for (int mi = 0; mi < 2; ++mi) {
                int rbase = bm + wr * 32 + mi * 16 + gq * 4;
#pragma unroll
                for (int q = 0; q < 4; ++q) {
                    int row = rbase + q;
                    if (row < NNODES) s += fmaxf(acc[mi][ni][q] + b, 0.f);
                }
            }
            atomicAdd(&csum[lcol], s);
        }
        __syncthreads();
        if (tid < 64) atomicAdd(&pool[bn + tid], csum[tid]);
    }
}

// ---------------- layer-0 input projection (parallel, multi-CU) ----------------
// pre0[t][j] = dot(pooled[t]/NNODES, Wih0[j]) + bih0[j] + bhh0[j]

__global__ void __launch_bounds__(128) pre0_kernel(const float* __restrict__ pooled,
        const float* __restrict__ Wih0, const float* __restrict__ bih0,
        const float* __restrict__ bhh0, float* __restrict__ pre0) {
    int j = blockIdx.x * 128 + threadIdx.x;
    const float4* w = (const float4*)(Wih0 + (size_t)j * HG);
    float acc[T_STEPS];
#pragma unroll
    for (int t = 0; t < T_STEPS; ++t) acc[t] = 0.f;
    for (int i = 0; i < 64; ++i) {
        float4 wv = w[i];
#pragma unroll
        for (int t = 0; t < T_STEPS; ++t) {
            float4 pv = *(const float4*)&pooled[t * HG + i * 4];
            acc[t] += pv.x * wv.x + pv.y * wv.y + pv.z * wv.z + pv.w * wv.w;
        }
    }
    float b = bih0[j] + bhh0[j];
#pragma unroll
    for (int t = 0; t < T_STEPS; ++t)
        pre0[t * 1024 + j] = acc[t] * (1.f / (float)NNODES) + b;
}

// ---------------- 2-layer LSTM, Whh register-resident, single block ----------------

__global__ void __launch_bounds__(1024) lstm2(
        const float* __restrict__ pre0,
        const float* __restrict__ Whh0, const float* __restrict__ Wih1,
        const float* __restrict__ Whh1,
        const float* __restrict__ bih1, const float* __restrict__ bhh1,
        const float* __restrict__ Wlin, const float* __restrict__ blin,
        float* __restrict__ out) {
    __shared__ float h[HG];
    __shared__ float gates[1024];
    __shared__ float hseq[T_STEPS][HG];
    int tid = threadIdx.x;
    const float4* h4 = (const float4*)h;
    float4 w[64];
    float c = 0.f;

    // ---- layer 0 recurrence (Whh0 rows in VGPRs) ----
    {
        const float4* wp = (const float4*)(Whh0 + (size_t)tid * HG);
#pragma unroll
        for (int i = 0; i < 64; ++i) w[i] = wp[i];
    }
    if (tid < HG) h[tid] = 0.f;
    __syncthreads();
    for (int t = 0; t < T_STEPS; ++t) {
        float a0 = 0.f, a1 = 0.f, a2 = 0.f, a3 = 0.f;
#pragma unroll
        for (int i = 0; i < 64; ++i) {
            float4 hv = h4[i];
            a0 += hv.x * w[i].x; a1 += hv.y * w[i].y;
            a2 += hv.z * w[i].z; a3 += hv.w * w[i].w;
        }
        gates[tid] = pre0[t * 1024 + tid] + a0 + a1 + a2 + a3;
        __syncthreads();
        if (tid < HG) {
            float ig = sigm(gates[tid]);
            float fg = sigm(gates[HG + tid]);
            float gg = tanhf(gates[2 * HG + tid]);
            float og = sigm(gates[3 * HG + tid]);
            c = fg * c + ig * gg;
            float hn = og * tanhf(c);
            h[tid] = hn;
            hseq[t][tid] = hn;
        }
        __syncthreads();
    }

    // ---- layer 1 input projection (from hseq in LDS, streaming Wih1) ----
    float pre1[T_STEPS];
#pragma unroll
    for (int t = 0; t < T_STEPS; ++t) pre1[t] = 0.f;
    {
        const float4* wi = (const float4*)(Wih1 + (size_t)tid * HG);
        for (int i = 0; i < 64; ++i) {
            float4 wv = wi[i];
#pragma unroll
            for (int t = 0; t < T_STEPS; ++t) {
                float4 hv = *(const float4*)&hseq[t][i * 4];
                pre1[t] += hv.x * wv.x + hv.y * wv.y + hv.z * wv.z + hv.w * wv.w;
            }
        }
    }
    float bias1 = bih1[tid] + bhh1[tid];

    // ---- layer 1 recurrence ----
    {
        const float4* wp = (const float4*)(Whh1 + (size_t)tid * HG);
#pragma unroll
        for (int i = 0; i < 64; ++i) w[i] = wp[i];
    }
    c = 0.f;
    if (tid < HG) h[tid] = 0.f;
    __syncthreads();
    for (int t = 0; t < T_STEPS; ++t) {
        float a0 = 0.f, a1 = 0.f, a2 = 0.f, a3 = 0.f;
#pragma unroll
        for (int i = 0; i < 64; ++i) {
            float4 hv = h4[i];
            a0 += hv.x * w[i].x; a1 += hv.y * w[i].y;
            a2 += hv.z * w[i].z; a3 += hv.w * w[i].w;
        }
        gates[tid] = pre1[t] + bias1 + a0 + a1 + a2 + a3;
        __syncthreads();
        if (tid < HG) {
            float ig = sigm(gates[tid]);
            float fg = sigm(gates[HG + tid]);
            float gg = tanhf(gates[2 * HG + tid]);
            float og = sigm(gates[3 * HG + tid]);
            c = fg * c + ig * gg;
            h[tid] = og * tanhf(c);
        }
        __syncthreads();
    }

    if (tid < 8) {
        float s = blin[tid];
        for (int k = 0; k < HG; ++k) s += h[k] * Wlin[tid * HG + k];
        out[tid] = s;
    }
}

// ---------------- orchestration ----------------

extern "C" void kernel_launch(void* const* d_in, const int* in_sizes, int n_in,
                              void* d_out, int out_size, void* d_ws, size_t ws_size,
                              hipStream_t stream) {
    const float* x    = (const float*)d_in[0];
    const int*   edges= (const int*)d_in[1];
    const float* W1   = (const float*)d_in[3];
    const float* b1   = (const float*)d_in[4];
    const float* W2   = (const float*)d_in[5];
    const float* b2   = (const float*)d_in[6];
    const float* Wih0 = (const float*)d_in[7];
    const float* Whh0 = (const float*)d_in[8];
    const float* bih0 = (const float*)d_in[9];
    const float* bhh0 = (const float*)d_in[10];
    const float* Wih1 = (const float*)d_in[11];
    const float* Whh1 = (const float*)d_in[12];
    const float* bih1 = (const float*)d_in[13];
    const float* bhh1 = (const float*)d_in[14];
    const float* Wlin = (const float*)d_in[15];
    const float* blin = (const float*)d_in[16];

    char* p = (char*)d_ws;
    auto alloc = [&](size_t bytes) -> char* {
        char* q = p; p += (bytes + 255) & ~(size_t)255; return q;
    };
    int*   hist     = (int*)  alloc(sizeof(int)   * T_STEPS * NNODES);
    int*   rowstart = (int*)  alloc(sizeof(int)   * T_STEPS * RS_STRIDE);
    float* dinv     = (float*)alloc(sizeof(float) * T_STEPS * NNODES);
    int*   col      = (int*)  alloc(sizeof(int)   * T_STEPS * NEDGES);
    u16*   agg1     = (u16*)  alloc(sizeof(u16)   * (size_t)MPAD * FIN);
    u16*   h1b      = (u16*)  alloc(sizeof(u16)   * (size_t)NNODES * HG);
    u16*   agg2     = (u16*)  alloc(sizeof(u16)   * (size_t)MPAD * HG);
    float* pooled   = (float*)alloc(sizeof(float) * T_STEPS * HG);
    u16*   W1t      = (u16*)  alloc(sizeof(u16)   * HG * FIN);
    u16*   W2t      = (u16*)  alloc(sizeof(u16)   * HG * HG);
    float* pre0     = (float*)alloc(sizeof(float) * T_STEPS * 1024);
    (void)ws_size; (void)in_sizes; (void)n_in; (void)out_size;

    hipMemsetAsync(hist, 0, sizeof(int) * T_STEPS * NNODES, stream);
    hipMemsetAsync(pooled, 0, sizeof(float) * T_STEPS * HG, stream);
    hipMemsetAsync(agg1 + (size_t)NNODES * FIN, 0, sizeof(u16) * (MPAD - NNODES) * FIN, stream);
    hipMemsetAsync(agg2 + (size_t)NNODES * HG, 0, sizeof(u16) * (MPAD - NNODES) * HG, stream);

    int tot = T_STEPS * NEDGES;
    hist_kernel<<<(tot + 255) / 256, 256, 0, stream>>>(edges, hist);
    scan_kernel<<<T_STEPS, 1024, 0, stream>>>(hist, rowstart, dinv);
    fill_kernel<<<(tot + 255) / 256, 256, 0, stream>>>(edges, rowstart, hist, col);
    convw_kernel<<<HG * FIN / 256, 256, 0, stream>>>(W1, W1t, FIN);
    convw_kernel<<<HG * HG  / 256, 256, 0, stream>>>(W2, W2t, HG);

    for (int t = 0; t < T_STEPS; ++t) {
        agg128<<<NNODES / 4, 256, 0, stream>>>(x + (size_t)t * NNODES * FIN,
                rowstart + t * RS_STRIDE, col + (size_t)t * NEDGES, dinv + t * NNODES, agg1);
        gemm_bf16<FIN, false><<<dim3(313, 4), 256, 0, stream>>>(agg1, W1t, b1, h1b, nullptr);
        agg256<<<NNODES / 4, 256, 0, stream>>>(h1b,
                rowstart + t * RS_STRIDE, col + (size_t)t * NEDGES, dinv + t * NNODES, agg2);
        gemm_bf16<HG, true><<<dim3(313, 4), 256, 0, stream>>>(agg2, W2t, b2, nullptr,
                pooled + t * HG);
    }
    pre0_kernel<<<8, 128, 0, stream>>>(pooled, Wih0, bih0, bhh0, pre0);
    lstm2<<<1, 1024, 0, stream>>>(pre0, Whh0, Wih1, Whh1, bih1, bhh1, Wlin, blin,
                                  (float*)d_out);
}

// Round 3
// 1578.141 us; speedup vs baseline: 1.8016x; 1.4962x over previous
//
#include <hip/hip_runtime.h>
#include <hip/hip_bf16.h>
#include <math.h>

#define T_STEPS 12
#define NNODES  20000
#define NEDGES  320000
#define MPAD    20032
#define FIN     128
#define HG      256
#define RS_STRIDE 20032

typedef unsigned short u16;
typedef unsigned int   u32;
using bf16x8 = __attribute__((ext_vector_type(8))) short;
using f32x4  = __attribute__((ext_vector_type(4))) float;

__device__ __forceinline__ float bf2f(u16 u) {
    union { u32 i; float f; } v; v.i = ((u32)u) << 16; return v.f;
}
__device__ __forceinline__ u16 f2bf(float f) {
    union { float f; u32 i; } v; v.f = f;
    u32 r = v.i + 0x7fffu + ((v.i >> 16) & 1u);
    return (u16)(r >> 16);
}
__device__ __forceinline__ u16 f2h(float f) {
    _Float16 h = (_Float16)f; u16 u; __builtin_memcpy(&u, &h, 2); return u;
}
__device__ __forceinline__ float h2f(u16 u) {
    _Float16 h; __builtin_memcpy(&h, &u, 2); return (float)h;
}
__device__ __forceinline__ void gload16(const void* g, void* l) {
    __builtin_amdgcn_global_load_lds(
        (const __attribute__((address_space(1))) u32*)g,
        (__attribute__((address_space(3))) u32*)l, 16, 0, 0);
}
__device__ __forceinline__ float sigm(float x) { return 1.f / (1.f + expf(-x)); }

// ---------------- CSR build (all 12 timesteps; verified R1/R2) ----------------

__global__ void hist_kernel(const int* __restrict__ edges, int* __restrict__ hist) {
    int idx = blockIdx.x * blockDim.x + threadIdx.x;
    if (idx >= T_STEPS * NEDGES) return;
    int t = idx / NEDGES, e = idx - t * NEDGES;
    int d = edges[t * 2 * NEDGES + NEDGES + e];
    atomicAdd(&hist[t * NNODES + d], 1);
}

__global__ void __launch_bounds__(1024) scan_kernel(int* __restrict__ hist,
        int* __restrict__ rowstart, float* __restrict__ dinv) {
    int t = blockIdx.x;
    int tid = threadIdx.x;
    __shared__ int buf[1024];
    __shared__ int carry_s;
    if (tid == 0) carry_s = 0;
    __syncthreads();
    for (int base = 0; base < NNODES; base += 1024) {
        int i = base + tid;
        int v = (i < NNODES) ? hist[t * NNODES + i] : 0;
        buf[tid] = v;
        __syncthreads();
        for (int off = 1; off < 1024; off <<= 1) {
            int add = (tid >= off) ? buf[tid - off] : 0;
            __syncthreads();
            buf[tid] += add;
            __syncthreads();
        }
        int incl = buf[tid];
        int excl = incl - v + carry_s;
        if (i < NNODES) {
            rowstart[t * RS_STRIDE + i] = excl;
            dinv[t * NNODES + i] = rsqrtf((float)(v + 1));
            hist[t * NNODES + i] = 0;
        }
        __syncthreads();
        if (tid == 1023) carry_s += incl;
        __syncthreads();
    }
    if (tid == 0) rowstart[t * RS_STRIDE + NNODES] = carry_s;
}

__global__ void fill_kernel(const int* __restrict__ edges, const int* __restrict__ rowstart,
        int* __restrict__ cursor, int* __restrict__ col) {
    int idx = blockIdx.x * blockDim.x + threadIdx.x;
    if (idx >= T_STEPS * NEDGES) return;
    int t = idx / NEDGES, e = idx - t * NEDGES;
    int s = edges[t * 2 * NEDGES + e];
    int d = edges[t * 2 * NEDGES + NEDGES + e];
    int pos = rowstart[t * RS_STRIDE + d] + atomicAdd(&cursor[t * NNODES + d], 1);
    col[t * NEDGES + pos] = s;
}

// ---------------- conversions ----------------

// W [K][256] fp32 -> Wt [256][K] bf16
__global__ void convw_kernel(const float* __restrict__ W, u16* __restrict__ Wt, int K) {
    int idx = blockIdx.x * blockDim.x + threadIdx.x;
    int n = idx / K, k = idx - n * K;
    Wt[idx] = f2bf(W[k * HG + n]);
}

// x fp32 -> bf16, flat
__global__ void x2bf_kernel(const float* __restrict__ x, u16* __restrict__ xb) {
    size_t idx = (size_t)(blockIdx.x * blockDim.x + threadIdx.x) * 4;
    float4 v = *(const float4*)&x[idx];
    ushort4 o; o.x = f2bf(v.x); o.y = f2bf(v.y); o.z = f2bf(v.z); o.w = f2bf(v.w);
    *(ushort4*)&xb[idx] = o;
}

// LSTM weights {Whh0, Wih1, Whh1} [1024][256] fp32 -> lane-coalesced fp16 [m][kb][1024][8]
__global__ void lconv_kernel(const float* __restrict__ Whh0, const float* __restrict__ Wih1,
        const float* __restrict__ Whh1, u16* __restrict__ lw) {
    int idx = blockIdx.x * blockDim.x + threadIdx.x;   // 3*1024*32
    int m = idx >> 15;
    int r = idx & 32767;
    int j = r >> 5, kb = r & 31;
    const float* src = (m == 0) ? Whh0 : (m == 1) ? Wih1 : Whh1;
    u16* dst = lw + m * 262144 + (kb * 1024 + j) * 8;
    const float4* s4 = (const float4*)(src + j * 256 + kb * 8);
    float4 a = s4[0], b = s4[1];
    dst[0] = f2h(a.x); dst[1] = f2h(a.y); dst[2] = f2h(a.z); dst[3] = f2h(a.w);
    dst[4] = f2h(b.x); dst[5] = f2h(b.y); dst[6] = f2h(b.z); dst[7] = f2h(b.w);
}

// ---------------- batched pull aggregation (G timesteps per dispatch) ----------------
// one wave per (t_loc, node_loc); pad nodes (node_loc >= NNODES) write zero rows

template <bool XB>
__global__ void __launch_bounds__(256) agg128(const float* __restrict__ xf,
        const u16* __restrict__ xb,
        const int* __restrict__ rowstart, const int* __restrict__ col,
        const float* __restrict__ dinv, u16* __restrict__ out) {
    int glob = (blockIdx.x << 2) + (threadIdx.x >> 6);
    int lane = threadIdx.x & 63;
    int t = glob / MPAD, node = glob - t * MPAD;
    u16* orow = out + ((size_t)glob) * FIN;
    if (node >= NNODES) { *(u32*)&orow[lane << 1] = 0; return; }
    float dn = dinv[t * NNODES + node];
    float ax, ay;
    if (XB) {
        u32 pv = *(const u32*)&xb[((size_t)t * NNODES + node) * FIN + (lane << 1)];
        ax = dn * bf2f((u16)pv); ay = dn * bf2f((u16)(pv >> 16));
    } else {
        float2 v = *(const float2*)&xf[((size_t)t * NNODES + node) * FIN + (lane << 1)];
        ax = dn * v.x; ay = dn * v.y;
    }
    int s0 = rowstart[t * RS_STRIDE + node], s1 = rowstart[t * RS_STRIDE + node + 1];
    for (int e = s0; e < s1; ++e) {
        int s = col[t * NEDGES + e];
        float ds = dinv[t * NNODES + s];
        if (XB) {
            u32 pv = *(const u32*)&xb[((size_t)t * NNODES + s) * FIN + (lane << 1)];
            ax += ds * bf2f((u16)pv); ay += ds * bf2f((u16)(pv >> 16));
        } else {
            float2 u = *(const float2*)&xf[((size_t)t * NNODES + s) * FIN + (lane << 1)];
            ax += ds * u.x; ay += ds * u.y;
        }
    }
    u32 packed = (u32)f2bf(dn * ax) | ((u32)f2bf(dn * ay) << 16);
    *(u32*)&orow[lane << 1] = packed;
}

__global__ void __launch_bounds__(256) agg256(const u16* __restrict__ xin,
        const int* __restrict__ rowstart, const int* __restrict__ col,
        const float* __restrict__ dinv, u16* __restrict__ out) {
    int glob = (blockIdx.x << 2) + (threadIdx.x >> 6);
    int lane = threadIdx.x & 63;
    int t = glob / MPAD, node = glob - t * MPAD;
    u16* orow = out + ((size_t)glob) * HG;
    if (node >= NNODES) { *(ushort4*)&orow[lane << 2] = make_ushort4(0, 0, 0, 0); return; }
    float dn = dinv[t * NNODES + node];
    ushort4 v = *(const ushort4*)&xin[((size_t)t * MPAD + node) * HG + (lane << 2)];
    float a0 = dn * bf2f(v.x), a1 = dn * bf2f(v.y), a2 = dn * bf2f(v.z), a3 = dn * bf2f(v.w);
    int s0 = rowstart[t * RS_STRIDE + node], s1 = rowstart[t * RS_STRIDE + node + 1];
    for (int e = s0; e < s1; ++e) {
        int s = col[t * NEDGES + e];
        float ds = dinv[t * NNODES + s];
        ushort4 u = *(const ushort4*)&xin[((size_t)t * MPAD + s) * HG + (lane << 2)];
        a0 += ds * bf2f(u.x); a1 += ds * bf2f(u.y); a2 += ds * bf2f(u.z); a3 += ds * bf2f(u.w);
    }
    ushort4 o;
    o.x = f2bf(dn * a0); o.y = f2bf(dn * a1); o.z = f2bf(dn * a2); o.w = f2bf(dn * a3);
    *(ushort4*)&orow[lane << 2] = o;
}

// ---------------- bf16 MFMA GEMM (verified R2 core), batched ----------------
// A [G*MPAD][K] bf16 (pad rows zero), Bt [256][K] bf16. 64x64 tile, BK=64.
// POOL: per-t column-sum of relu into pool[t][256] (excludes pad rows).

template <int K, bool POOL>
__global__ __launch_bounds__(256) void gemm_bf16(
        const u16* __restrict__ A, const u16* __restrict__ Bt,
        const float* __restrict__ bias,
        u16* __restrict__ C, float* __restrict__ pool) {
    __shared__ u16 As[64 * 64];
    __shared__ u16 Bs[64 * 64];
    __shared__ float csum[64];
    int tid = threadIdx.x;
    int bm = blockIdx.x * 64, bn = blockIdx.y * 64;
    int t8 = tid >> 3, sl = tid & 7;
    int lane = tid & 63, wid = tid >> 6;
    int wr = wid >> 1, wc = wid & 1;
    int r0 = lane & 15, gq = lane >> 4;

    f32x4 acc[2][2] = {};

    for (int k0 = 0; k0 < K; k0 += 64) {
#pragma unroll
        for (int i = 0; i < 2; ++i) {
            int r = i * 32 + t8;
            int ch = sl ^ (r & 7);
            gload16(A  + (size_t)(bm + r) * K + k0 + ch * 8, &As[i * 2048 + tid * 8]);
            gload16(Bt + (size_t)(bn + r) * K + k0 + ch * 8, &Bs[i * 2048 + tid * 8]);
        }
        __syncthreads();
#pragma unroll
        for (int kk = 0; kk < 2; ++kk) {
            bf16x8 a[2], b[2];
#pragma unroll
            for (int mi = 0; mi < 2; ++mi) {
                int R = wr * 32 + mi * 16 + r0;
                int s = (kk * 4 + gq) ^ (R & 7);
                a[mi] = *(const bf16x8*)&As[R * 64 + s * 8];
            }
#pragma unroll
            for (int ni = 0; ni < 2; ++ni) {
                int R = wc * 32 + ni * 16 + r0;
                int s = (kk * 4 + gq) ^ (R & 7);
                b[ni] = *(const bf16x8*)&Bs[R * 64 + s * 8];
            }
#pragma unroll
            for (int mi = 0; mi < 2; ++mi)
#pragma unroll
                for (int ni = 0; ni < 2; ++ni)
                    acc[mi][ni] = __builtin_amdgcn_mfma_f32_16x16x32_bf16(
                        a[mi], b[ni], acc[mi][ni], 0, 0, 0);
        }
        __syncthreads();
    }

    if (!POOL) {
#pragma unroll
        for (int ni = 0; ni < 2; ++ni) {
            int colg = bn + wc * 32 + ni * 16 + r0;
            float b = bias[colg];
#pragma unroll
            for (int mi = 0; mi < 2; ++mi) {
                int rbase = bm + wr * 32 + mi * 16 + gq * 4;
#pragma unroll
                for (int q = 0; q < 4; ++q) {
                    int row = rbase + q;
                    C[(size_t)row * HG + colg] = f2bf(fmaxf(acc[mi][ni][q] + b, 0.f));
                }
            }
        }
    } else {
        int tblk = blockIdx.x / 313;            // 313 M-tiles per timestep
        if (tid < 64) csum[tid] = 0.f;
        __syncthreads();
#pragma unroll
        for (int ni = 0; ni < 2; ++ni) {
            int lcol = wc * 32 + ni * 16 + r0;
            float b = bias[bn + lcol];
            float s = 0.f;
#pragma unroll
            for (int mi = 0; mi < 2; ++mi) {
                int rbase = bm + wr * 32 + mi * 16 + gq * 4;
#pragma unroll
                for (int q = 0; q < 4; ++q) {
                    int row = rbase + q;
                    int rloc = row - tblk * MPAD;
                    if (rloc < NNODES) s += fmaxf(acc[mi][ni][q] + b, 0.f);
                }
            }
            atomicAdd(&csum[lcol], s);
        }
        __syncthreads();
        if (tid < 64) atomicAdd(&pool[tblk * HG + bn + tid], csum[tid]);
    }
}

// ---------------- layer-0 input projection (verified R2) ----------------

__global__ void __launch_bounds__(128) pre0_kernel(const float* __restrict__ pooled,
        const float* __restrict__ Wih0, const float* __restrict__ bih0,
        const float* __restrict__ bhh0, float* __restrict__ pre0) {
    int j = blockIdx.x * 128 + threadIdx.x;
    const float4* w = (const float4*)(Wih0 + (size_t)j * HG);
    float acc[T_STEPS];
#pragma unroll
    for (int t = 0; t < T_STEPS; ++t) acc[t] = 0.f;
    for (int i = 0; i < 64; ++i) {
        float4 wv = w[i];
#pragma unroll
        for (int t = 0; t < T_STEPS; ++t) {
            float4 pv = *(const float4*)&pooled[t * HG + i * 4];
            acc[t] += pv.x * wv.x + pv.y * wv.y + pv.z * wv.z + pv.w * wv.w;
        }
    }
    float b = bih0[j] + bhh0[j];
#pragma unroll
    for (int t = 0; t < T_STEPS; ++t)
        pre0[t * 1024 + j] = acc[t] * (1.f / (float)NNODES) + b;
}

// ---------------- 2-layer LSTM: fp16 weights streamed coalesced from L2 ----------------
// lw layout: [m][kb 0..31][j 0..1023][8] fp16, m = {Whh0, Wih1, Whh1}

__global__ void __launch_bounds__(1024) lstm2(
        const float* __restrict__ pre0, const u16* __restrict__ lw,
        const float* __restrict__ bih1, const float* __restrict__ bhh1,
        const float* __restrict__ Wlin, const float* __restrict__ blin,
        float* __restrict__ out) {
    __shared__ float h[HG];
    __shared__ float gates[1024];
    __shared__ float hseq[T_STEPS][HG];
    int tid = threadIdx.x;
    const float4* h4 = (const float4*)h;
    const u16* Whh0c = lw;
    const u16* Wih1c = lw + 262144;
    const u16* Whh1c = lw + 524288;
    float c = 0.f;

    if (tid < HG) h[tid] = 0.f;
    __syncthreads();
    // ---- layer 0 recurrence ----
    for (int t = 0; t < T_STEPS; ++t) {
        float acc = 0.f;
#pragma unroll 8
        for (int kb = 0; kb < 32; ++kb) {
            ushort4 wa = *(const ushort4*)&Whh0c[(kb * 1024 + tid) * 8];
            ushort4 wb = *(const ushort4*)&Whh0c[(kb * 1024 + tid) * 8 + 4];
            float4 ha = h4[kb * 2], hb = h4[kb * 2 + 1];
            acc += h2f(wa.x) * ha.x + h2f(wa.y) * ha.y + h2f(wa.z) * ha.z + h2f(wa.w) * ha.w
                 + h2f(wb.x) * hb.x + h2f(wb.y) * hb.y + h2f(wb.z) * hb.z + h2f(wb.w) * hb.w;
        }
        gates[tid] = pre0[t * 1024 + tid] + acc;
        __syncthreads();
        if (tid < HG) {
            float ig = sigm(gates[tid]);
            float fg = sigm(gates[HG + tid]);
            float gg = tanhf(gates[2 * HG + tid]);
            float og = sigm(gates[3 * HG + tid]);
            c = fg * c + ig * gg;
            float hn = og * tanhf(c);
            h[tid] = hn;
            hseq[t][tid] = hn;
        }
        __syncthreads();
    }

    // ---- layer 1 input projection from hseq ----
    float pre1[T_STEPS];
#pragma unroll
    for (int t = 0; t < T_STEPS; ++t) pre1[t] = 0.f;
    for (int kb = 0; kb < 32; ++kb) {
        ushort4 wa = *(const ushort4*)&Wih1c[(kb * 1024 + tid) * 8];
        ushort4 wb = *(const ushort4*)&Wih1c[(kb * 1024 + tid) * 8 + 4];
        float w0 = h2f(wa.x), w1 = h2f(wa.y), w2 = h2f(wa.z), w3 = h2f(wa.w);
        float w4 = h2f(wb.x), w5 = h2f(wb.y), w6 = h2f(wb.z), w7 = h2f(wb.w);
#pragma unroll
        for (int t = 0; t < T_STEPS; ++t) {
            float4 ha = *(const float4*)&hseq[t][kb * 8];
            float4 hb = *(const float4*)&hseq[t][kb * 8 + 4];
            pre1[t] += w0 * ha.x + w1 * ha.y + w2 * ha.z + w3 * ha.w
                     + w4 * hb.x + w5 * hb.y + w6 * hb.z + w7 * hb.w;
        }
    }
    float bias1 = bih1[tid] + bhh1[tid];

    // ---- layer 1 recurrence ----
    c = 0.f;
    if (tid < HG) h[tid] = 0.f;
    __syncthreads();
    for (int t = 0; t < T_STEPS; ++t) {
        float acc = 0.f;
#pragma unroll 8
        for (int kb = 0; kb < 32; ++kb) {
            ushort4 wa = *(const ushort4*)&Whh1c[(kb * 1024 + tid) * 8];
            ushort4 wb = *(const ushort4*)&Whh1c[(kb * 1024 + tid) * 8 + 4];
            float4 ha = h4[kb * 2], hb = h4[kb * 2 + 1];
            acc += h2f(wa.x) * ha.x + h2f(wa.y) * ha.y + h2f(wa.z) * ha.z + h2f(wa.w) * ha.w
                 + h2f(wb.x) * hb.x + h2f(wb.y) * hb.y + h2f(wb.z) * hb.z + h2f(wb.w) * hb.w;
        }
        gates[tid] = pre1[t] + bias1 + acc;
        __syncthreads();
        if (tid < HG) {
            float ig = sigm(gates[tid]);
            float fg = sigm(gates[HG + tid]);
            float gg = tanhf(gates[2 * HG + tid]);
            float og = sigm(gates[3 * HG + tid]);
            c = fg * c + ig * gg;
            h[tid] = og * tanhf(c);
        }
        __syncthreads();
    }

    if (tid < 8) {
        float s = blin[tid];
        for (int k = 0; k < HG; ++k) s += h[k] * Wlin[tid * HG + k];
        out[tid] = s;
    }
}

// ---------------- orchestration ----------------

extern "C" void kernel_launch(void* const* d_in, const int* in_sizes, int n_in,
                              void* d_out, int out_size, void* d_ws, size_t ws_size,
                              hipStream_t stream) {
    const float* x    = (const float*)d_in[0];
    const int*   edges= (const int*)d_in[1];
    const float* W1   = (const float*)d_in[3];
    const float* b1   = (const float*)d_in[4];
    const float* W2   = (const float*)d_in[5];
    const float* b2   = (const float*)d_in[6];
    const float* Wih0 = (const float*)d_in[7];
    const float* Whh0 = (const float*)d_in[8];
    const float* bih0 = (const float*)d_in[9];
    const float* bhh0 = (const float*)d_in[10];
    const float* Wih1 = (const float*)d_in[11];
    const float* Whh1 = (const float*)d_in[12];
    const float* bih1 = (const float*)d_in[13];
    const float* bhh1 = (const float*)d_in[14];
    const float* Wlin = (const float*)d_in[15];
    const float* blin = (const float*)d_in[16];
    (void)in_sizes; (void)n_in; (void)out_size;

    char* p = (char*)d_ws;
    auto alloc = [&](size_t bytes) -> char* {
        char* q = p; p += (bytes + 255) & ~(size_t)255; return q;
    };
    // fixed allocations
    int*   hist     = (int*)  alloc(sizeof(int)   * T_STEPS * NNODES);
    int*   rowstart = (int*)  alloc(sizeof(int)   * T_STEPS * RS_STRIDE);
    float* dinv     = (float*)alloc(sizeof(float) * T_STEPS * NNODES);
    int*   col      = (int*)  alloc(sizeof(int)   * T_STEPS * NEDGES);
    float* pooled   = (float*)alloc(sizeof(float) * T_STEPS * HG);
    u16*   W1t      = (u16*)  alloc(sizeof(u16)   * HG * FIN);
    u16*   W2t      = (u16*)  alloc(sizeof(u16)   * HG * HG);
    u16*   lw       = (u16*)  alloc(sizeof(u16)   * 3 * 262144);
    float* pre0     = (float*)alloc(sizeof(float) * T_STEPS * 1024);
    size_t fixed_used = (size_t)(p - (char*)d_ws);

    // adaptive group size G and optional x->bf16 conversion
    const size_t xb_bytes  = sizeof(u16) * (size_t)T_STEPS * NNODES * FIN;
    const size_t per_g     = (size_t)MPAD * HG * 2 * 2;   // h1b + agg union, per timestep
    const size_t slack     = 4096 * 16;
    static const int gopts[6] = {12, 6, 4, 3, 2, 1};
    int G = 0; bool use_xb = true;
    for (int i = 0; i < 6; ++i)
        if (fixed_used + xb_bytes + per_g * gopts[i] + slack <= ws_size) { G = gopts[i]; break; }
    if (G == 0) {
        use_xb = false;
        for (int i = 0; i < 6; ++i)
            if (fixed_used + per_g * gopts[i] + slack <= ws_size) { G = gopts[i]; break; }
        if (G == 0) G = 1;   // minimal config (~40 MB); R1/R2 proved >=75 MB works
    }
    u16* xb   = use_xb ? (u16*)alloc(xb_bytes) : nullptr;
    u16* h1b  = (u16*)alloc(sizeof(u16) * (size_t)G * MPAD * HG);
    u16* aggu = (u16*)alloc(sizeof(u16) * (size_t)G * MPAD * HG);  // agg1 & agg2 alias

    hipMemsetAsync(hist, 0, sizeof(int) * T_STEPS * NNODES, stream);
    hipMemsetAsync(pooled, 0, sizeof(float) * T_STEPS * HG, stream);

    int tot = T_STEPS * NEDGES;
    hist_kernel<<<(tot + 255) / 256, 256, 0, stream>>>(edges, hist);
    scan_kernel<<<T_STEPS, 1024, 0, stream>>>(hist, rowstart, dinv);
    fill_kernel<<<(tot + 255) / 256, 256, 0, stream>>>(edges, rowstart, hist, col);
    convw_kernel<<<HG * FIN / 256, 256, 0, stream>>>(W1, W1t, FIN);
    convw_kernel<<<HG * HG  / 256, 256, 0, stream>>>(W2, W2t, HG);
    lconv_kernel<<<3 * 32768 / 256, 256, 0, stream>>>(Whh0, Wih1, Whh1, lw);
    if (use_xb)
        x2bf_kernel<<<(int)((size_t)T_STEPS * NNODES * FIN / 4 / 256), 256, 0, stream>>>(x, xb);

    for (int g = 0; g < T_STEPS / G; ++g) {
        int t0 = g * G;
        const float* xg  = x  + (size_t)t0 * NNODES * FIN;
        const u16*   xbg = use_xb ? xb + (size_t)t0 * NNODES * FIN : nullptr;
        const int*   rsg = rowstart + (size_t)t0 * RS_STRIDE;
        const int*   clg = col + (size_t)t0 * NEDGES;
        const float* dvg = dinv + (size_t)t0 * NNODES;
        int nagg = G * MPAD / 4;
        if (use_xb)
            agg128<true><<<nagg, 256, 0, stream>>>(nullptr, xbg, rsg, clg, dvg, aggu);
        else
            agg128<false><<<nagg, 256, 0, stream>>>(xg, nullptr, rsg, clg, dvg, aggu);
        gemm_bf16<FIN, false><<<dim3(G * 313, 4), 256, 0, stream>>>(aggu, W1t, b1, h1b, nullptr);
        agg256<<<nagg, 256, 0, stream>>>(h1b, rsg, clg, dvg, aggu);
        gemm_bf16<HG, true><<<dim3(G * 313, 4), 256, 0, stream>>>(aggu, W2t, b2, nullptr,
                pooled + (size_t)t0 * HG);
    }
    pre0_kernel<<<8, 128, 0, stream>>>(pooled, Wih0, bih0, bhh0, pre0);
    lstm2<<<1, 1024, 0, stream>>>(pre0, lw, bih1, bhh1, Wlin, blin, (float*)d_out);
}

// Round 4
// 1220.691 us; speedup vs baseline: 2.3291x; 1.2928x over previous
//
#include <hip/hip_runtime.h>
#include <hip/hip_bf16.h>
#include <math.h>

#define T_STEPS 12
#define NNODES  20000
#define NEDGES  320000
#define MPAD    20032
#define FIN     128
#define HG      256
#define RS_STRIDE 20032

typedef unsigned short u16;
typedef unsigned int   u32;
using bf16x8 = __attribute__((ext_vector_type(8))) short;
using f32x4  = __attribute__((ext_vector_type(4))) float;

__device__ __forceinline__ float bf2f(u16 u) {
    union { u32 i; float f; } v; v.i = ((u32)u) << 16; return v.f;
}
__device__ __forceinline__ u16 f2bf(float f) {
    union { float f; u32 i; } v; v.f = f;
    u32 r = v.i + 0x7fffu + ((v.i >> 16) & 1u);
    return (u16)(r >> 16);
}
__device__ __forceinline__ u16 f2h(float f) {
    _Float16 h = (_Float16)f; u16 u; __builtin_memcpy(&u, &h, 2); return u;
}
__device__ __forceinline__ float h2f(u16 u) {
    _Float16 h; __builtin_memcpy(&h, &u, 2); return (float)h;
}
__device__ __forceinline__ void gload16(const void* g, void* l) {
    __builtin_amdgcn_global_load_lds(
        (const __attribute__((address_space(1))) u32*)g,
        (__attribute__((address_space(3))) u32*)l, 16, 0, 0);
}
__device__ __forceinline__ float sigm(float x) { return 1.f / (1.f + expf(-x)); }

// ---------------- CSR build (verified R1-R3) ----------------

__global__ void hist_kernel(const int* __restrict__ edges, int* __restrict__ hist) {
    int idx = blockIdx.x * blockDim.x + threadIdx.x;
    if (idx >= T_STEPS * NEDGES) return;
    int t = idx / NEDGES, e = idx - t * NEDGES;
    int d = edges[t * 2 * NEDGES + NEDGES + e];
    atomicAdd(&hist[t * NNODES + d], 1);
}

__global__ void __launch_bounds__(1024) scan_kernel(int* __restrict__ hist,
        int* __restrict__ rowstart, float* __restrict__ dinv) {
    int t = blockIdx.x;
    int tid = threadIdx.x;
    __shared__ int buf[1024];
    __shared__ int carry_s;
    if (tid == 0) carry_s = 0;
    __syncthreads();
    for (int base = 0; base < NNODES; base += 1024) {
        int i = base + tid;
        int v = (i < NNODES) ? hist[t * NNODES + i] : 0;
        buf[tid] = v;
        __syncthreads();
        for (int off = 1; off < 1024; off <<= 1) {
            int add = (tid >= off) ? buf[tid - off] : 0;
            __syncthreads();
            buf[tid] += add;
            __syncthreads();
        }
        int incl = buf[tid];
        int excl = incl - v + carry_s;
        if (i < NNODES) {
            rowstart[t * RS_STRIDE + i] = excl;
            dinv[t * NNODES + i] = rsqrtf((float)(v + 1));
            hist[t * NNODES + i] = 0;
        }
        __syncthreads();
        if (tid == 1023) carry_s += incl;
        __syncthreads();
    }
    if (tid == 0) rowstart[t * RS_STRIDE + NNODES] = carry_s;
}

__global__ void fill_kernel(const int* __restrict__ edges, const int* __restrict__ rowstart,
        int* __restrict__ cursor, int* __restrict__ col) {
    int idx = blockIdx.x * blockDim.x + threadIdx.x;
    if (idx >= T_STEPS * NEDGES) return;
    int t = idx / NEDGES, e = idx - t * NEDGES;
    int s = edges[t * 2 * NEDGES + e];
    int d = edges[t * 2 * NEDGES + NEDGES + e];
    int pos = rowstart[t * RS_STRIDE + d] + atomicAdd(&cursor[t * NNODES + d], 1);
    col[t * NEDGES + pos] = s;
}

// ---------------- conversions ----------------

// W [K][256] fp32 -> Wt [256][K] bf16
__global__ void convw_kernel(const float* __restrict__ W, u16* __restrict__ Wt, int K) {
    int idx = blockIdx.x * blockDim.x + threadIdx.x;
    int n = idx / K, k = idx - n * K;
    Wt[idx] = f2bf(W[k * HG + n]);
}

// x fp32 -> bf16 PREMULTIPLIED by dinv: xb[t][n] = dinv[t][n] * x[t][n]
// 32 threads per row (128 dims / 4 per thread); row = t*NNODES+n indexes dinv flat.
__global__ void x2bf_kernel(const float* __restrict__ x, const float* __restrict__ dinv,
        u16* __restrict__ xb) {
    int idx = blockIdx.x * blockDim.x + threadIdx.x;
    int row = idx >> 5, q = (idx & 31) << 2;
    float dn = dinv[row];
    float4 v = *(const float4*)&x[(size_t)row * FIN + q];
    ushort4 o;
    o.x = f2bf(dn * v.x); o.y = f2bf(dn * v.y);
    o.z = f2bf(dn * v.z); o.w = f2bf(dn * v.w);
    *(ushort4*)&xb[(size_t)row * FIN + q] = o;
}

// LSTM weights {Whh0, Wih1, Whh1} [1024][256] fp32 -> lane-coalesced fp16 [m][kb][1024][8]
__global__ void lconv_kernel(const float* __restrict__ Whh0, const float* __restrict__ Wih1,
        const float* __restrict__ Whh1, u16* __restrict__ lw) {
    int idx = blockIdx.x * blockDim.x + threadIdx.x;   // 3*1024*32
    int m = idx >> 15;
    int r = idx & 32767;
    int j = r >> 5, kb = r & 31;
    const float* src = (m == 0) ? Whh0 : (m == 1) ? Wih1 : Whh1;
    u16* dst = lw + m * 262144 + (kb * 1024 + j) * 8;
    const float4* s4 = (const float4*)(src + j * 256 + kb * 8);
    float4 a = s4[0], b = s4[1];
    dst[0] = f2h(a.x); dst[1] = f2h(a.y); dst[2] = f2h(a.z); dst[3] = f2h(a.w);
    dst[4] = f2h(b.x); dst[5] = f2h(b.y); dst[6] = f2h(b.z); dst[7] = f2h(b.w);
}

// ---------------- batched pull aggregation, 8-wide pipelined gather ----------------
// rows are PRE-SCALED by dinv; out[d] = dinv[d] * (row[d] + sum_{s->d} row[s]).

__global__ void __launch_bounds__(256) agg128(const u16* __restrict__ xb,
        const int* __restrict__ rowstart, const int* __restrict__ col,
        const float* __restrict__ dinv, u16* __restrict__ out) {
    int glob = (blockIdx.x << 2) + (threadIdx.x >> 6);
    int lane = threadIdx.x & 63;
    int t = glob / MPAD, node = glob - t * MPAD;
    u16* orow = out + ((size_t)glob) * FIN;
    if (node >= NNODES) { *(u32*)&orow[lane << 1] = 0; return; }
    const u16* xt = xb + (size_t)t * NNODES * FIN;
    const int* cb = col + (size_t)t * NEDGES;
    int o2 = lane << 1;
    u32 pv = *(const u32*)&xt[(size_t)node * FIN + o2];
    float ax = bf2f((u16)pv), ay = bf2f((u16)(pv >> 16));
    int s0 = rowstart[t * RS_STRIDE + node], s1 = rowstart[t * RS_STRIDE + node + 1];
    int e = s0;
    for (; e + 8 <= s1; e += 8) {
        int ix[8]; u32 rv[8];
#pragma unroll
        for (int j = 0; j < 8; ++j) ix[j] = cb[e + j];
#pragma unroll
        for (int j = 0; j < 8; ++j) rv[j] = *(const u32*)&xt[(size_t)ix[j] * FIN + o2];
#pragma unroll
        for (int j = 0; j < 8; ++j) {
            ax += bf2f((u16)rv[j]); ay += bf2f((u16)(rv[j] >> 16));
        }
    }
    for (; e + 4 <= s1; e += 4) {
        int ix[4]; u32 rv[4];
#pragma unroll
        for (int j = 0; j < 4; ++j) ix[j] = cb[e + j];
#pragma unroll
        for (int j = 0; j < 4; ++j) rv[j] = *(const u32*)&xt[(size_t)ix[j] * FIN + o2];
#pragma unroll
        for (int j = 0; j < 4; ++j) {
            ax += bf2f((u16)rv[j]); ay += bf2f((u16)(rv[j] >> 16));
        }
    }
    for (; e < s1; ++e) {
        u32 rv = *(const u32*)&xt[(size_t)cb[e] * FIN + o2];
        ax += bf2f((u16)rv); ay += bf2f((u16)(rv >> 16));
    }
    float dn = dinv[t * NNODES + node];
    u32 packed = (u32)f2bf(dn * ax) | ((u32)f2bf(dn * ay) << 16);
    *(u32*)&orow[o2] = packed;
}

__global__ void __launch_bounds__(256) agg256(const u16* __restrict__ xin,
        const int* __restrict__ rowstart, const int* __restrict__ col,
        const float* __restrict__ dinv, u16* __restrict__ out) {
    int glob = (blockIdx.x << 2) + (threadIdx.x >> 6);
    int lane = threadIdx.x & 63;
    int t = glob / MPAD, node = glob - t * MPAD;
    u16* orow = out + ((size_t)glob) * HG;
    if (node >= NNODES) { *(ushort4*)&orow[lane << 2] = make_ushort4(0, 0, 0, 0); return; }
    const u16* xt = xin + (size_t)t * MPAD * HG;   // h1s rows, stride MPAD per t
    const int* cb = col + (size_t)t * NEDGES;
    int o4 = lane << 2;
    ushort4 v = *(const ushort4*)&xt[(size_t)node * HG + o4];
    float a0 = bf2f(v.x), a1 = bf2f(v.y), a2 = bf2f(v.z), a3 = bf2f(v.w);
    int s0 = rowstart[t * RS_STRIDE + node], s1 = rowstart[t * RS_STRIDE + node + 1];
    int e = s0;
    for (; e + 8 <= s1; e += 8) {
        int ix[8]; ushort4 rv[8];
#pragma unroll
        for (int j = 0; j < 8; ++j) ix[j] = cb[e + j];
#pragma unroll
        for (int j = 0; j < 8; ++j) rv[j] = *(const ushort4*)&xt[(size_t)ix[j] * HG + o4];
#pragma unroll
        for (int j = 0; j < 8; ++j) {
            a0 += bf2f(rv[j].x); a1 += bf2f(rv[j].y);
            a2 += bf2f(rv[j].z); a3 += bf2f(rv[j].w);
        }
    }
    for (; e + 4 <= s1; e += 4) {
        int ix[4]; ushort4 rv[4];
#pragma unroll
        for (int j = 0; j < 4; ++j) ix[j] = cb[e + j];
#pragma unroll
        for (int j = 0; j < 4; ++j) rv[j] = *(const ushort4*)&xt[(size_t)ix[j] * HG + o4];
#pragma unroll
        for (int j = 0; j < 4; ++j) {
            a0 += bf2f(rv[j].x); a1 += bf2f(rv[j].y);
            a2 += bf2f(rv[j].z); a3 += bf2f(rv[j].w);
        }
    }
    for (; e < s1; ++e) {
        ushort4 rv = *(const ushort4*)&xt[(size_t)cb[e] * HG + o4];
        a0 += bf2f(rv.x); a1 += bf2f(rv.y); a2 += bf2f(rv.z); a3 += bf2f(rv.w);
    }
    float dn = dinv[t * NNODES + node];
    ushort4 o;
    o.x = f2bf(dn * a0); o.y = f2bf(dn * a1); o.z = f2bf(dn * a2); o.w = f2bf(dn * a3);
    *(ushort4*)&orow[o4] = o;
}

// ---------------- bf16 MFMA GEMM (verified R2/R3 core) ----------------
// A [G*MPAD][K] bf16 (pad rows zero), Bt [256][K] bf16. 64x64 tile, BK=64.
// !POOL: C[row] = bf16( dscale[row] * relu(acc+bias) ), pad rows -> 0.
// POOL:  per-t column-sum of relu into pool[t][256] (excludes pad rows).

template <int K, bool POOL>
__global__ __launch_bounds__(256) void gemm_bf16(
        const u16* __restrict__ A, const u16* __restrict__ Bt,
        const float* __restrict__ bias, const float* __restrict__ dscale,
        u16* __restrict__ C, float* __restrict__ pool) {
    __shared__ u16 As[64 * 64];
    __shared__ u16 Bs[64 * 64];
    __shared__ float csum[64];
    int tid = threadIdx.x;
    int bm = blockIdx.x * 64, bn = blockIdx.y * 64;
    int t8 = tid >> 3, sl = tid & 7;
    int lane = tid & 63, wid = tid >> 6;
    int wr = wid >> 1, wc = wid & 1;
    int r0 = lane & 15, gq = lane >> 4;
    int tblk = blockIdx.x / 313;            // 313 M-tiles per timestep

    f32x4 acc[2][2] = {};

    for (int k0 = 0; k0 < K; k0 += 64) {
#pragma unroll
        for (int i = 0; i < 2; ++i) {
            int r = i * 32 + t8;
            int ch = sl ^ (r & 7);
            gload16(A  + (size_t)(bm + r) * K + k0 + ch * 8, &As[i * 2048 + tid * 8]);
            gload16(Bt + (size_t)(bn + r) * K + k0 + ch * 8, &Bs[i * 2048 + tid * 8]);
        }
        __syncthreads();
#pragma unroll
        for (int kk = 0; kk < 2; ++kk) {
            bf16x8 a[2], b[2];
#pragma unroll
            for (int mi = 0; mi < 2; ++mi) {
                int R = wr * 32 + mi * 16 + r0;
                int s = (kk * 4 + gq) ^ (R & 7);
                a[mi] = *(const bf16x8*)&As[R * 64 + s * 8];
            }
#pragma unroll
            for (int ni = 0; ni < 2; ++ni) {
                int R = wc * 32 + ni * 16 + r0;
                int s = (kk * 4 + gq) ^ (R & 7);
                b[ni] = *(const bf16x8*)&Bs[R * 64 + s * 8];
            }
#pragma unroll
            for (int mi = 0; mi < 2; ++mi)
#pragma unroll
                for (int ni = 0; ni < 2; ++ni)
                    acc[mi][ni] = __builtin_amdgcn_mfma_f32_16x16x32_bf16(
                        a[mi], b[ni], acc[mi][ni], 0, 0, 0);
        }
        __syncthreads();
    }

    if (!POOL) {
#pragma unroll
        for (int ni = 0; ni < 2; ++ni) {
            int colg = bn + wc * 32 + ni * 16 + r0;
            float b = bias[colg];
#pragma unroll
            for (int mi = 0; mi < 2; ++mi) {
                int rbase = bm + wr * 32 + mi * 16 + gq * 4;
#pragma unroll
                for (int q = 0; q < 4; ++q) {
                    int row = rbase + q;
                    int rloc = row - tblk * MPAD;
                    float sc = (rloc < NNODES) ? dscale[tblk * NNODES + rloc] : 0.f;
                    C[(size_t)row * HG + colg] = f2bf(sc * fmaxf(acc[mi][ni][q] + b, 0.f));
                }
            }
        }
    } else {
        if (tid < 64) csum[tid] = 0.f;
        __syncthreads();
#pragma unroll
        for (int ni = 0; ni < 2; ++ni) {
            int lcol = wc * 32 + ni * 16 + r0;
            float b = bias[bn + lcol];
            float s = 0.f;
#pragma unroll
            for (int mi = 0; mi < 2; ++mi) {
                int rbase = bm + wr * 32 + mi * 16 + gq * 4;
#pragma unroll
                for (int q = 0; q < 4; ++q) {
                    int row = rbase + q;
                    int rloc = row - tblk * MPAD;
                    if (rloc < NNODES) s += fmaxf(acc[mi][ni][q] + b, 0.f);
                }
            }
            atomicAdd(&csum[lcol], s);
        }
        __syncthreads();
        if (tid < 64) atomicAdd(&pool[tblk * HG + bn + tid], csum[tid]);
    }
}

// ---------------- layer-0 input projection (verified R2) ----------------

__global__ void __launch_bounds__(128) pre0_kernel(const float* __restrict__ pooled,
        const float* __restrict__ Wih0, const float* __restrict__ bih0,
        const float* __restrict__ bhh0, float* __restrict__ pre0) {
    int j = blockIdx.x * 128 + threadIdx.x;
    const float4* w = (const float4*)(Wih0 + (size_t)j * HG);
    float acc[T_STEPS];
#pragma unroll
    for (int t = 0; t < T_STEPS; ++t) acc[t] = 0.f;
    for (int i = 0; i < 64; ++i) {
        float4 wv = w[i];
#pragma unroll
        for (int t = 0; t < T_STEPS; ++t) {
            float4 pv = *(const float4*)&pooled[t * HG + i * 4];
            acc[t] += pv.x * wv.x + pv.y * wv.y + pv.z * wv.z + pv.w * wv.w;
        }
    }
    float b = bih0[j] + bhh0[j];
#pragma unroll
    for (int t = 0; t < T_STEPS; ++t)
        pre0[t * 1024 + j] = acc[t] * (1.f / (float)NNODES) + b;
}

// ---------------- 2-layer LSTM: fp16 weights streamed coalesced (verified R3) ----------------

__global__ void __launch_bounds__(1024) lstm2(
        const float* __restrict__ pre0, const u16* __restrict__ lw,
        const float* __restrict__ bih1, const float* __restrict__ bhh1,
        const float* __restrict__ Wlin, const float* __restrict__ blin,
        float* __restrict__ out) {
    __shared__ float h[HG];
    __shared__ float gates[1024];
    __shared__ float hseq[T_STEPS][HG];
    int tid = threadIdx.x;
    const float4* h4 = (const float4*)h;
    const u16* Whh0c = lw;
    const u16* Wih1c = lw + 262144;
    const u16* Whh1c = lw + 524288;
    float c = 0.f;

    if (tid < HG) h[tid] = 0.f;
    __syncthreads();
    for (int t = 0; t < T_STEPS; ++t) {
        float acc = 0.f;
#pragma unroll 8
        for (int kb = 0; kb < 32; ++kb) {
            ushort4 wa = *(const ushort4*)&Whh0c[(kb * 1024 + tid) * 8];
            ushort4 wb = *(const ushort4*)&Whh0c[(kb * 1024 + tid) * 8 + 4];
            float4 ha = h4[kb * 2], hb = h4[kb * 2 + 1];
            acc += h2f(wa.x) * ha.x + h2f(wa.y) * ha.y + h2f(wa.z) * ha.z + h2f(wa.w) * ha.w
                 + h2f(wb.x) * hb.x + h2f(wb.y) * hb.y + h2f(wb.z) * hb.z + h2f(wb.w) * hb.w;
        }
        gates[tid] = pre0[t * 1024 + tid] + acc;
        __syncthreads();
        if (tid < HG) {
            float ig = sigm(gates[tid]);
            float fg = sigm(gates[HG + tid]);
            float gg = tanhf(gates[2 * HG + tid]);
            float og = sigm(gates[3 * HG + tid]);
            c = fg * c + ig * gg;
            float hn = og * tanhf(c);
            h[tid] = hn;
            hseq[t][tid] = hn;
        }
        __syncthreads();
    }

    float pre1[T_STEPS];
#pragma unroll
    for (int t = 0; t < T_STEPS; ++t) pre1[t] = 0.f;
    for (int kb = 0; kb < 32; ++kb) {
        ushort4 wa = *(const ushort4*)&Wih1c[(kb * 1024 + tid) * 8];
        ushort4 wb = *(const ushort4*)&Wih1c[(kb * 1024 + tid) * 8 + 4];
        float w0 = h2f(wa.x), w1 = h2f(wa.y), w2 = h2f(wa.z), w3 = h2f(wa.w);
        float w4 = h2f(wb.x), w5 = h2f(wb.y), w6 = h2f(wb.z), w7 = h2f(wb.w);
#pragma unroll
        for (int t = 0; t < T_STEPS; ++t) {
            float4 ha = *(const float4*)&hseq[t][kb * 8];
            float4 hb = *(const float4*)&hseq[t][kb * 8 + 4];
            pre1[t] += w0 * ha.x + w1 * ha.y + w2 * ha.z + w3 * ha.w
                     + w4 * hb.x + w5 * hb.y + w6 * hb.z + w7 * hb.w;
        }
    }
    float bias1 = bih1[tid] + bhh1[tid];

    c = 0.f;
    if (tid < HG) h[tid] = 0.f;
    __syncthreads();
    for (int t = 0; t < T_STEPS; ++t) {
        float acc = 0.f;
#pragma unroll 8
        for (int kb = 0; kb < 32; ++kb) {
            ushort4 wa = *(const ushort4*)&Whh1c[(kb * 1024 + tid) * 8];
            ushort4 wb = *(const ushort4*)&Whh1c[(kb * 1024 + tid) * 8 + 4];
            float4 ha = h4[kb * 2], hb = h4[kb * 2 + 1];
            acc += h2f(wa.x) * ha.x + h2f(wa.y) * ha.y + h2f(wa.z) * ha.z + h2f(wa.w) * ha.w
                 + h2f(wb.x) * hb.x + h2f(wb.y) * hb.y + h2f(wb.z) * hb.z + h2f(wb.w) * hb.w;
        }
        gates[tid] = pre1[t] + bias1 + acc;
        __syncthreads();
        if (tid < HG) {
            float ig = sigm(gates[tid]);
            float fg = sigm(gates[HG + tid]);
            float gg = tanhf(gates[2 * HG + tid]);
            float og = sigm(gates[3 * HG + tid]);
            c = fg * c + ig * gg;
            h[tid] = og * tanhf(c);
        }
        __syncthreads();
    }

    if (tid < 8) {
        float s = blin[tid];
        for (int k = 0; k < HG; ++k) s += h[k] * Wlin[tid * HG + k];
        out[tid] = s;
    }
}

// ---------------- orchestration ----------------

extern "C" void kernel_launch(void* const* d_in, const int* in_sizes, int n_in,
                              void* d_out, int out_size, void* d_ws, size_t ws_size,
                              hipStream_t stream) {
    const float* x    = (const float*)d_in[0];
    const int*   edges= (const int*)d_in[1];
    const float* W1   = (const float*)d_in[3];
    const float* b1   = (const float*)d_in[4];
    const float* W2   = (const float*)d_in[5];
    const float* b2   = (const float*)d_in[6];
    const float* Wih0 = (const float*)d_in[7];
    const float* Whh0 = (const float*)d_in[8];
    const float* bih0 = (const float*)d_in[9];
    const float* bhh0 = (const float*)d_in[10];
    const float* Wih1 = (const float*)d_in[11];
    const float* Whh1 = (const float*)d_in[12];
    const float* bih1 = (const float*)d_in[13];
    const float* bhh1 = (const float*)d_in[14];
    const float* Wlin = (const float*)d_in[15];
    const float* blin = (const float*)d_in[16];
    (void)in_sizes; (void)n_in; (void)out_size;

    char* p = (char*)d_ws;
    auto alloc = [&](size_t bytes) -> char* {
        char* q = p; p += (bytes + 255) & ~(size_t)255; return q;
    };
    int*   hist     = (int*)  alloc(sizeof(int)   * T_STEPS * NNODES);
    int*   rowstart = (int*)  alloc(sizeof(int)   * T_STEPS * RS_STRIDE);
    float* dinv     = (float*)alloc(sizeof(float) * T_STEPS * NNODES);
    int*   col      = (int*)  alloc(sizeof(int)   * T_STEPS * NEDGES);
    float* pooled   = (float*)alloc(sizeof(float) * T_STEPS * HG);
    u16*   W1t      = (u16*)  alloc(sizeof(u16)   * HG * FIN);
    u16*   W2t      = (u16*)  alloc(sizeof(u16)   * HG * HG);
    u16*   lw       = (u16*)  alloc(sizeof(u16)   * 3 * 262144);
    float* pre0     = (float*)alloc(sizeof(float) * T_STEPS * 1024);
    size_t fixed_used = (size_t)(p - (char*)d_ws);

    // adaptive group size G (xb is required now: premultiplied bf16 x)
    const size_t xb_bytes  = sizeof(u16) * (size_t)T_STEPS * NNODES * FIN;
    const size_t per_g     = (size_t)MPAD * HG * 2 * 2;   // h1b + agg union, per timestep
    const size_t slack     = 4096 * 16;
    static const int gopts[6] = {12, 6, 4, 3, 2, 1};
    int G = 1;
    for (int i = 0; i < 6; ++i)
        if (fixed_used + xb_bytes + per_g * gopts[i] + slack <= ws_size) { G = gopts[i]; break; }
    u16* xb   = (u16*)alloc(xb_bytes);
    u16* h1b  = (u16*)alloc(sizeof(u16) * (size_t)G * MPAD * HG);
    u16* aggu = (u16*)alloc(sizeof(u16) * (size_t)G * MPAD * HG);  // agg1 & agg2 alias

    hipMemsetAsync(hist, 0, sizeof(int) * T_STEPS * NNODES, stream);
    hipMemsetAsync(pooled, 0, sizeof(float) * T_STEPS * HG, stream);

    int tot = T_STEPS * NEDGES;
    hist_kernel<<<(tot + 255) / 256, 256, 0, stream>>>(edges, hist);
    scan_kernel<<<T_STEPS, 1024, 0, stream>>>(hist, rowstart, dinv);
    fill_kernel<<<(tot + 255) / 256, 256, 0, stream>>>(edges, rowstart, hist, col);
    convw_kernel<<<HG * FIN / 256, 256, 0, stream>>>(W1, W1t, FIN);
    convw_kernel<<<HG * HG  / 256, 256, 0, stream>>>(W2, W2t, HG);
    lconv_kernel<<<3 * 32768 / 256, 256, 0, stream>>>(Whh0, Wih1, Whh1, lw);
    x2bf_kernel<<<T_STEPS * NNODES * 32 / 256, 256, 0, stream>>>(x, dinv, xb);

    for (int g = 0; g < T_STEPS / G; ++g) {
        int t0 = g * G;
        const u16*   xbg = xb + (size_t)t0 * NNODES * FIN;
        const int*   rsg = rowstart + (size_t)t0 * RS_STRIDE;
        const int*   clg = col + (size_t)t0 * NEDGES;
        const float* dvg = dinv + (size_t)t0 * NNODES;
        int nagg = G * MPAD / 4;
        agg128<<<nagg, 256, 0, stream>>>(xbg, rsg, clg, dvg, aggu);
        gemm_bf16<FIN, false><<<dim3(G * 313, 4), 256, 0, stream>>>(aggu, W1t, b1, dvg,
                h1b, nullptr);
        agg256<<<nagg, 256, 0, stream>>>(h1b, rsg, clg, dvg, aggu);
        gemm_bf16<HG, true><<<dim3(G * 313, 4), 256, 0, stream>>>(aggu, W2t, b2, nullptr,
                nullptr, pooled + (size_t)t0 * HG);
    }
    pre0_kernel<<<8, 128, 0, stream>>>(pooled, Wih0, bih0, bhh0, pre0);
    lstm2<<<1, 1024, 0, stream>>>(pre0, lw, bih1, bhh1, Wlin, blin, (float*)d_out);
}

// Round 5
// 1152.310 us; speedup vs baseline: 2.4673x; 1.0593x over previous
//
#include <hip/hip_runtime.h>
#include <hip/hip_bf16.h>
#include <math.h>

#define T_STEPS 12
#define NNODES  20000
#define NEDGES  320000
#define MPAD    20032
#define FIN     128
#define HG      256
#define RS_STRIDE 20032

typedef unsigned short u16;
typedef unsigned int   u32;
using bf16x8 = __attribute__((ext_vector_type(8))) short;
using f32x4  = __attribute__((ext_vector_type(4))) float;

__device__ __forceinline__ float bf2f(u16 u) {
    union { u32 i; float f; } v; v.i = ((u32)u) << 16; return v.f;
}
__device__ __forceinline__ u16 f2bf(float f) {
    union { float f; u32 i; } v; v.f = f;
    u32 r = v.i + 0x7fffu + ((v.i >> 16) & 1u);
    return (u16)(r >> 16);
}
__device__ __forceinline__ u16 f2h(float f) {
    _Float16 h = (_Float16)f; u16 u; __builtin_memcpy(&u, &h, 2); return u;
}
__device__ __forceinline__ float h2f(u16 u) {
    _Float16 h; __builtin_memcpy(&h, &u, 2); return (float)h;
}
__device__ __forceinline__ void gload16(const void* g, void* l) {
    __builtin_amdgcn_global_load_lds(
        (const __attribute__((address_space(1))) u32*)g,
        (__attribute__((address_space(3))) u32*)l, 16, 0, 0);
}
__device__ __forceinline__ float sigm(float x) { return 1.f / (1.f + expf(-x)); }
__device__ __forceinline__ void astore(float* p, float v) {
    __hip_atomic_store(p, v, __ATOMIC_RELAXED, __HIP_MEMORY_SCOPE_AGENT);
}
__device__ __forceinline__ float aload(const float* p) {
    return __hip_atomic_load(p, __ATOMIC_RELAXED, __HIP_MEMORY_SCOPE_AGENT);
}

// ---------------- CSR build (verified R1-R4) ----------------

__global__ void hist_kernel(const int* __restrict__ edges, int* __restrict__ hist) {
    int idx = blockIdx.x * blockDim.x + threadIdx.x;
    if (idx >= T_STEPS * NEDGES) return;
    int t = idx / NEDGES, e = idx - t * NEDGES;
    int d = edges[t * 2 * NEDGES + NEDGES + e];
    atomicAdd(&hist[t * NNODES + d], 1);
}

__global__ void __launch_bounds__(1024) scan_kernel(int* __restrict__ hist,
        int* __restrict__ rowstart, float* __restrict__ dinv) {
    int t = blockIdx.x;
    int tid = threadIdx.x;
    __shared__ int buf[1024];
    __shared__ int carry_s;
    if (tid == 0) carry_s = 0;
    __syncthreads();
    for (int base = 0; base < NNODES; base += 1024) {
        int i = base + tid;
        int v = (i < NNODES) ? hist[t * NNODES + i] : 0;
        buf[tid] = v;
        __syncthreads();
        for (int off = 1; off < 1024; off <<= 1) {
            int add = (tid >= off) ? buf[tid - off] : 0;
            __syncthreads();
            buf[tid] += add;
            __syncthreads();
        }
        int incl = buf[tid];
        int excl = incl - v + carry_s;
        if (i < NNODES) {
            rowstart[t * RS_STRIDE + i] = excl;
            dinv[t * NNODES + i] = rsqrtf((float)(v + 1));
            hist[t * NNODES + i] = 0;
        }
        __syncthreads();
        if (tid == 1023) carry_s += incl;
        __syncthreads();
    }
    if (tid == 0) rowstart[t * RS_STRIDE + NNODES] = carry_s;
}

__global__ void fill_kernel(const int* __restrict__ edges, const int* __restrict__ rowstart,
        int* __restrict__ cursor, int* __restrict__ col) {
    int idx = blockIdx.x * blockDim.x + threadIdx.x;
    if (idx >= T_STEPS * NEDGES) return;
    int t = idx / NEDGES, e = idx - t * NEDGES;
    int s = edges[t * 2 * NEDGES + e];
    int d = edges[t * 2 * NEDGES + NEDGES + e];
    int pos = rowstart[t * RS_STRIDE + d] + atomicAdd(&cursor[t * NNODES + d], 1);
    col[t * NEDGES + pos] = s;
}

// ---------------- conversions ----------------

__global__ void convw_kernel(const float* __restrict__ W, u16* __restrict__ Wt, int K) {
    int idx = blockIdx.x * blockDim.x + threadIdx.x;
    int n = idx / K, k = idx - n * K;
    Wt[idx] = f2bf(W[k * HG + n]);
}

// x fp32 -> bf16 premultiplied by dinv
__global__ void x2bf_kernel(const float* __restrict__ x, const float* __restrict__ dinv,
        u16* __restrict__ xb) {
    int idx = blockIdx.x * blockDim.x + threadIdx.x;
    int row = idx >> 5, q = (idx & 31) << 2;
    float dn = dinv[row];
    float4 v = *(const float4*)&x[(size_t)row * FIN + q];
    ushort4 o;
    o.x = f2bf(dn * v.x); o.y = f2bf(dn * v.y);
    o.z = f2bf(dn * v.z); o.w = f2bf(dn * v.w);
    *(ushort4*)&xb[(size_t)row * FIN + q] = o;
}

// ---------------- batched pull aggregation, 16-wide pipelined gather ----------------

__global__ void __launch_bounds__(256) agg128(const u16* __restrict__ xb,
        const int* __restrict__ rowstart, const int* __restrict__ col,
        const float* __restrict__ dinv, u16* __restrict__ out) {
    int glob = (blockIdx.x << 2) + (threadIdx.x >> 6);
    int lane = threadIdx.x & 63;
    int t = glob / MPAD, node = glob - t * MPAD;
    u16* orow = out + ((size_t)glob) * FIN;
    if (node >= NNODES) { *(u32*)&orow[lane << 1] = 0; return; }
    const u16* xt = xb + (size_t)t * NNODES * FIN;
    const int* cb = col + (size_t)t * NEDGES;
    int o2 = lane << 1;
    u32 pv = *(const u32*)&xt[(size_t)node * FIN + o2];
    float ax = bf2f((u16)pv), ay = bf2f((u16)(pv >> 16));
    int s0 = rowstart[t * RS_STRIDE + node], s1 = rowstart[t * RS_STRIDE + node + 1];
    int e = s0;
    for (; e + 16 <= s1; e += 16) {
        int ix[16]; u32 rv[16];
#pragma unroll
        for (int j = 0; j < 16; ++j) ix[j] = cb[e + j];
#pragma unroll
        for (int j = 0; j < 16; ++j) rv[j] = *(const u32*)&xt[(size_t)ix[j] * FIN + o2];
#pragma unroll
        for (int j = 0; j < 16; ++j) {
            ax += bf2f((u16)rv[j]); ay += bf2f((u16)(rv[j] >> 16));
        }
    }
    for (; e + 4 <= s1; e += 4) {
        int ix[4]; u32 rv[4];
#pragma unroll
        for (int j = 0; j < 4; ++j) ix[j] = cb[e + j];
#pragma unroll
        for (int j = 0; j < 4; ++j) rv[j] = *(const u32*)&xt[(size_t)ix[j] * FIN + o2];
#pragma unroll
        for (int j = 0; j < 4; ++j) {
            ax += bf2f((u16)rv[j]); ay += bf2f((u16)(rv[j] >> 16));
        }
    }
    for (; e < s1; ++e) {
        u32 rv = *(const u32*)&xt[(size_t)cb[e] * FIN + o2];
        ax += bf2f((u16)rv); ay += bf2f((u16)(rv >> 16));
    }
    float dn = dinv[t * NNODES + node];
    u32 packed = (u32)f2bf(dn * ax) | ((u32)f2bf(dn * ay) << 16);
    *(u32*)&orow[o2] = packed;
}

__global__ void __launch_bounds__(256) agg256(const u16* __restrict__ xin,
        const int* __restrict__ rowstart, const int* __restrict__ col,
        const float* __restrict__ dinv, u16* __restrict__ out) {
    int glob = (blockIdx.x << 2) + (threadIdx.x >> 6);
    int lane = threadIdx.x & 63;
    int t = glob / MPAD, node = glob - t * MPAD;
    u16* orow = out + ((size_t)glob) * HG;
    if (node >= NNODES) { *(ushort4*)&orow[lane << 2] = make_ushort4(0, 0, 0, 0); return; }
    const u16* xt = xin + (size_t)t * MPAD * HG;
    const int* cb = col + (size_t)t * NEDGES;
    int o4 = lane << 2;
    ushort4 v = *(const ushort4*)&xt[(size_t)node * HG + o4];
    float a0 = bf2f(v.x), a1 = bf2f(v.y), a2 = bf2f(v.z), a3 = bf2f(v.w);
    int s0 = rowstart[t * RS_STRIDE + node], s1 = rowstart[t * RS_STRIDE + node + 1];
    int e = s0;
    for (; e + 16 <= s1; e += 16) {
        int ix[16]; ushort4 rv[16];
#pragma unroll
        for (int j = 0; j < 16; ++j) ix[j] = cb[e + j];
#pragma unroll
        for (int j = 0; j < 16; ++j) rv[j] = *(const ushort4*)&xt[(size_t)ix[j] * HG + o4];
#pragma unroll
        for (int j = 0; j < 16; ++j) {
            a0 += bf2f(rv[j].x); a1 += bf2f(rv[j].y);
            a2 += bf2f(rv[j].z); a3 += bf2f(rv[j].w);
        }
    }
    for (; e + 4 <= s1; e += 4) {
        int ix[4]; ushort4 rv[4];
#pragma unroll
        for (int j = 0; j < 4; ++j) ix[j] = cb[e + j];
#pragma unroll
        for (int j = 0; j < 4; ++j) rv[j] = *(const ushort4*)&xt[(size_t)ix[j] * HG + o4];
#pragma unroll
        for (int j = 0; j < 4; ++j) {
            a0 += bf2f(rv[j].x); a1 += bf2f(rv[j].y);
            a2 += bf2f(rv[j].z); a3 += bf2f(rv[j].w);
        }
    }
    for (; e < s1; ++e) {
        ushort4 rv = *(const ushort4*)&xt[(size_t)cb[e] * HG + o4];
        a0 += bf2f(rv.x); a1 += bf2f(rv.y); a2 += bf2f(rv.z); a3 += bf2f(rv.w);
    }
    float dn = dinv[t * NNODES + node];
    ushort4 o;
    o.x = f2bf(dn * a0); o.y = f2bf(dn * a1); o.z = f2bf(dn * a2); o.w = f2bf(dn * a3);
    *(ushort4*)&orow[o4] = o;
}

// ---------------- bf16 MFMA GEMM (verified R2-R4 core) ----------------

template <int K, bool POOL>
__global__ __launch_bounds__(256) void gemm_bf16(
        const u16* __restrict__ A, const u16* __restrict__ Bt,
        const float* __restrict__ bias, const float* __restrict__ dscale,
        u16* __restrict__ C, float* __restrict__ pool) {
    __shared__ u16 As[64 * 64];
    __shared__ u16 Bs[64 * 64];
    __shared__ float csum[64];
    int tid = threadIdx.x;
    int bm = blockIdx.x * 64, bn = blockIdx.y * 64;
    int t8 = tid >> 3, sl = tid & 7;
    int lane = tid & 63, wid = tid >> 6;
    int wr = wid >> 1, wc = wid & 1;
    int r0 = lane & 15, gq = lane >> 4;
    int tblk = blockIdx.x / 313;

    f32x4 acc[2][2] = {};

    for (int k0 = 0; k0 < K; k0 += 64) {
#pragma unroll
        for (int i = 0; i < 2; ++i) {
            int r = i * 32 + t8;
            int ch = sl ^ (r & 7);
            gload16(A  + (size_t)(bm + r) * K + k0 + ch * 8, &As[i * 2048 + tid * 8]);
            gload16(Bt + (size_t)(bn + r) * K + k0 + ch * 8, &Bs[i * 2048 + tid * 8]);
        }
        __syncthreads();
#pragma unroll
        for (int kk = 0; kk < 2; ++kk) {
            bf16x8 a[2], b[2];
#pragma unroll
            for (int mi = 0; mi < 2; ++mi) {
                int R = wr * 32 + mi * 16 + r0;
                int s = (kk * 4 + gq) ^ (R & 7);
                a[mi] = *(const bf16x8*)&As[R * 64 + s * 8];
            }
#pragma unroll
            for (int ni = 0; ni < 2; ++ni) {
                int R = wc * 32 + ni * 16 + r0;
                int s = (kk * 4 + gq) ^ (R & 7);
                b[ni] = *(const bf16x8*)&Bs[R * 64 + s * 8];
            }
#pragma unroll
            for (int mi = 0; mi < 2; ++mi)
#pragma unroll
                for (int ni = 0; ni < 2; ++ni)
                    acc[mi][ni] = __builtin_amdgcn_mfma_f32_16x16x32_bf16(
                        a[mi], b[ni], acc[mi][ni], 0, 0, 0);
        }
        __syncthreads();
    }

    if (!POOL) {
#pragma unroll
        for (int ni = 0; ni < 2; ++ni) {
            int colg = bn + wc * 32 + ni * 16 + r0;
            float b = bias[colg];
#pragma unroll
            for (int mi = 0; mi < 2; ++mi) {
                int rbase = bm + wr * 32 + mi * 16 + gq * 4;
#pragma unroll
                for (int q = 0; q < 4; ++q) {
                    int row = rbase + q;
                    int rloc = row - tblk * MPAD;
                    float sc = (rloc < NNODES) ? dscale[tblk * NNODES + rloc] : 0.f;
                    C[(size_t)row * HG + colg] = f2bf(sc * fmaxf(acc[mi][ni][q] + b, 0.f));
                }
            }
        }
    } else {
        if (tid < 64) csum[tid] = 0.f;
        __syncthreads();
#pragma unroll
        for (int ni = 0; ni < 2; ++ni) {
            int lcol = wc * 32 + ni * 16 + r0;
            float b = bias[bn + lcol];
            float s = 0.f;
#pragma unroll
            for (int mi = 0; mi < 2; ++mi) {
                int rbase = bm + wr * 32 + mi * 16 + gq * 4;
#pragma unroll
                for (int q = 0; q < 4; ++q) {
                    int row = rbase + q;
                    int rloc = row - tblk * MPAD;
                    if (rloc < NNODES) s += fmaxf(acc[mi][ni][q] + b, 0.f);
                }
            }
            atomicAdd(&csum[lcol], s);
        }
        __syncthreads();
        if (tid < 64) atomicAdd(&pool[tblk * HG + bn + tid], csum[tid]);
    }
}

// ---------------- layer-0 input projection (verified R2-R4) ----------------

__global__ void __launch_bounds__(128) pre0_kernel(const float* __restrict__ pooled,
        const float* __restrict__ Wih0, const float* __restrict__ bih0,
        const float* __restrict__ bhh0, float* __restrict__ pre0) {
    int j = blockIdx.x * 128 + threadIdx.x;
    const float4* w = (const float4*)(Wih0 + (size_t)j * HG);
    float acc[T_STEPS];
#pragma unroll
    for (int t = 0; t < T_STEPS; ++t) acc[t] = 0.f;
    for (int i = 0; i < 64; ++i) {
        float4 wv = w[i];
#pragma unroll
        for (int t = 0; t < T_STEPS; ++t) {
            float4 pv = *(const float4*)&pooled[t * HG + i * 4];
            acc[t] += pv.x * wv.x + pv.y * wv.y + pv.z * wv.z + pv.w * wv.w;
        }
    }
    float b = bih0[j] + bhh0[j];
#pragma unroll
    for (int t = 0; t < T_STEPS; ++t)
        pre0[t * 1024 + j] = acc[t] * (1.f / (float)NNODES) + b;
}

// ---------------- 4-block cooperative LSTM ----------------
// Block b owns 64 hidden units (ubase = b*64) = 256 gate rows; each thread owns one
// gate row, weights (256 fp16) held in 128 VGPRs. Per-step h exchange through
// device-scope atomics (hbuf double-buffered) + per-block flag (release/acquire).

__device__ __forceinline__ void run_layer(const float* __restrict__ W,
        const float* preSrc, int preStride,
        int r, int tid, int b, int sbase, bool save_hseq,
        float* hl, float* garr,
        float* hbuf, float* hseq_glob, int* flags) {
    int u = tid & 63;
    u32 wreg[128];
    {
        const float4* src = (const float4*)(W + (size_t)r * HG);
#pragma unroll
        for (int i = 0; i < 64; ++i) {
            float4 v = src[i];
            wreg[2 * i]     = (u32)f2h(v.x) | ((u32)f2h(v.y) << 16);
            wreg[2 * i + 1] = (u32)f2h(v.z) | ((u32)f2h(v.w) << 16);
        }
    }
    float c = 0.f;
    hl[tid] = 0.f;
    __syncthreads();
    for (int t = 0; t < T_STEPS; ++t) {
        int s = sbase + t + 1;
        float pv = preSrc[t * preStride];    // issued early, consumed at the end
        float acc = 0.f;
#pragma unroll
        for (int k2 = 0; k2 < 128; ++k2) {
            u32 w = wreg[k2];
            float2 hv = *(const float2*)&hl[k2 * 2];
            acc += h2f((u16)w) * hv.x + h2f((u16)(w >> 16)) * hv.y;
        }
        garr[tid] = acc + pv;
        __syncthreads();
        if (tid < 64) {
            float ig = sigm(garr[u]);
            float fg = sigm(garr[64 + u]);
            float gg = tanhf(garr[128 + u]);
            float og = sigm(garr[192 + u]);
            c = fg * c + ig * gg;
            float hn = og * tanhf(c);
            astore(&hbuf[(s & 1) * 256 + b * 64 + u], hn);
            if (save_hseq) astore(&hseq_glob[t * 256 + b * 64 + u], hn);
        }
        if (tid == 0)
            __hip_atomic_store(&flags[b], s, __ATOMIC_RELEASE, __HIP_MEMORY_SCOPE_AGENT);
        if (tid < 4) {
            while (__hip_atomic_load(&flags[tid], __ATOMIC_ACQUIRE,
                                     __HIP_MEMORY_SCOPE_AGENT) < s)
                __builtin_amdgcn_s_sleep(1);
        }
        __syncthreads();
        hl[tid] = aload(&hbuf[(s & 1) * 256 + tid]);
        __syncthreads();
    }
}

__global__ void __launch_bounds__(256, 1) lstm4(
        const float* __restrict__ pre0,
        const float* __restrict__ Whh0, const float* __restrict__ Wih1,
        const float* __restrict__ Whh1,
        const float* __restrict__ bih1, const float* __restrict__ bhh1,
        const float* __restrict__ Wlin, const float* __restrict__ blin,
        float* hbuf, float* hseq_glob, int* flags,
        float* __restrict__ out) {
    __shared__ float hseqL[T_STEPS * 256];
    __shared__ float pre1L[T_STEPS * 256];
    __shared__ float hl[256];
    __shared__ float garr[256];
    int tid = threadIdx.x;
    int b = blockIdx.x;
    int g = tid >> 6, u = tid & 63;
    int r = g * 256 + b * 64 + u;

    // ---- layer 0 (pre from pre0_kernel; bias folded there) ----
    run_layer(Whh0, pre0 + r, 1024, r, tid, b, 0, true,
              hl, garr, hbuf, hseq_glob, flags);

    // ---- gather hseq (visible: flags>=12 acquired in last step) ----
    for (int i = tid; i < T_STEPS * 256; i += 256)
        hseqL[i] = aload(&hseq_glob[i]);
    __syncthreads();

    // ---- layer-1 input projection: fp32, row r of Wih1 ----
    {
        float pre1[T_STEPS];
#pragma unroll
        for (int t = 0; t < T_STEPS; ++t) pre1[t] = 0.f;
        const float4* src = (const float4*)(Wih1 + (size_t)r * HG);
        for (int i = 0; i < 64; ++i) {
            float4 wv = src[i];
#pragma unroll
            for (int t = 0; t < T_STEPS; ++t) {
                float4 hv = *(const float4*)&hseqL[t * 256 + i * 4];
                pre1[t] += wv.x * hv.x + wv.y * hv.y + wv.z * hv.z + wv.w * hv.w;
            }
        }
        float bias1 = bih1[r] + bhh1[r];
        __syncthreads();
#pragma unroll
        for (int t = 0; t < T_STEPS; ++t) pre1L[t * 256 + tid] = pre1[t] + bias1;
        __syncthreads();
    }

    // ---- layer 1 ----
    run_layer(Whh1, pre1L + tid, 256, r, tid, b, T_STEPS, false,
              hl, garr, hbuf, hseq_glob, flags);

    // ---- final linear (block 0): hl holds h(24) ----
    if (b == 0) {
        float hv = hl[tid];
        for (int j = 0; j < 8; ++j) {
            garr[tid] = hv * Wlin[j * 256 + tid];
            __syncthreads();
            if (tid < 128) garr[tid] += garr[tid + 128];
            __syncthreads();
            if (tid < 64) {
                float v = garr[tid] + garr[tid + 64];
                for (int off = 32; off; off >>= 1) v += __shfl_down(v, off);
                if (tid == 0) out[j] = v + blin[j];
            }
            __syncthreads();
        }
    }
}

// ---------------- orchestration ----------------

extern "C" void kernel_launch(void* const* d_in, const int* in_sizes, int n_in,
                              void* d_out, int out_size, void* d_ws, size_t ws_size,
                              hipStream_t stream) {
    const float* x    = (const float*)d_in[0];
    const int*   edges= (const int*)d_in[1];
    const float* W1   = (const float*)d_in[3];
    const float* b1   = (const float*)d_in[4];
    const float* W2   = (const float*)d_in[5];
    const float* b2   = (const float*)d_in[6];
    const float* Wih0 = (const float*)d_in[7];
    const float* Whh0 = (const float*)d_in[8];
    const float* bih0 = (const float*)d_in[9];
    const float* bhh0 = (const float*)d_in[10];
    const float* Wih1 = (const float*)d_in[11];
    const float* Whh1 = (const float*)d_in[12];
    const float* bih1 = (const float*)d_in[13];
    const float* bhh1 = (const float*)d_in[14];
    const float* Wlin = (const float*)d_in[15];
    const float* blin = (const float*)d_in[16];
    (void)in_sizes; (void)n_in; (void)out_size;

    char* p = (char*)d_ws;
    auto alloc = [&](size_t bytes) -> char* {
        char* q = p; p += (bytes + 255) & ~(size_t)255; return q;
    };
    int*   hist     = (int*)  alloc(sizeof(int)   * T_STEPS * NNODES);
    int*   rowstart = (int*)  alloc(sizeof(int)   * T_STEPS * RS_STRIDE);
    float* dinv     = (float*)alloc(sizeof(float) * T_STEPS * NNODES);
    int*   col      = (int*)  alloc(sizeof(int)   * T_STEPS * NEDGES);
    float* pooled   = (float*)alloc(sizeof(float) * T_STEPS * HG);
    u16*   W1t      = (u16*)  alloc(sizeof(u16)   * HG * FIN);
    u16*   W2t      = (u16*)  alloc(sizeof(u16)   * HG * HG);
    float* pre0     = (float*)alloc(sizeof(float) * T_STEPS * 1024);
    float* hbuf     = (float*)alloc(sizeof(float) * 2 * 256);
    float* hseq_g   = (float*)alloc(sizeof(float) * T_STEPS * 256);
    int*   flags    = (int*)  alloc(sizeof(int)   * 4);
    size_t fixed_used = (size_t)(p - (char*)d_ws);

    const size_t xb_bytes  = sizeof(u16) * (size_t)T_STEPS * NNODES * FIN;
    const size_t per_g     = (size_t)MPAD * HG * 2 * 2;
    const size_t slack     = 4096 * 16;
    static const int gopts[6] = {12, 6, 4, 3, 2, 1};
    int G = 1;
    for (int i = 0; i < 6; ++i)
        if (fixed_used + xb_bytes + per_g * gopts[i] + slack <= ws_size) { G = gopts[i]; break; }
    u16* xb   = (u16*)alloc(xb_bytes);
    u16* h1b  = (u16*)alloc(sizeof(u16) * (size_t)G * MPAD * HG);
    u16* aggu = (u16*)alloc(sizeof(u16) * (size_t)G * MPAD * HG);

    hipMemsetAsync(hist, 0, sizeof(int) * T_STEPS * NNODES, stream);
    hipMemsetAsync(pooled, 0, sizeof(float) * T_STEPS * HG, stream);
    hipMemsetAsync(flags, 0, sizeof(int) * 4, stream);

    int tot = T_STEPS * NEDGES;
    hist_kernel<<<(tot + 255) / 256, 256, 0, stream>>>(edges, hist);
    scan_kernel<<<T_STEPS, 1024, 0, stream>>>(hist, rowstart, dinv);
    fill_kernel<<<(tot + 255) / 256, 256, 0, stream>>>(edges, rowstart, hist, col);
    convw_kernel<<<HG * FIN / 256, 256, 0, stream>>>(W1, W1t, FIN);
    convw_kernel<<<HG * HG  / 256, 256, 0, stream>>>(W2, W2t, HG);
    x2bf_kernel<<<T_STEPS * NNODES * 32 / 256, 256, 0, stream>>>(x, dinv, xb);

    for (int g = 0; g < T_STEPS / G; ++g) {
        int t0 = g * G;
        const u16*   xbg = xb + (size_t)t0 * NNODES * FIN;
        const int*   rsg = rowstart + (size_t)t0 * RS_STRIDE;
        const int*   clg = col + (size_t)t0 * NEDGES;
        const float* dvg = dinv + (size_t)t0 * NNODES;
        int nagg = G * MPAD / 4;
        agg128<<<nagg, 256, 0, stream>>>(xbg, rsg, clg, dvg, aggu);
        gemm_bf16<FIN, false><<<dim3(G * 313, 4), 256, 0, stream>>>(aggu, W1t, b1, dvg,
                h1b, nullptr);
        agg256<<<nagg, 256, 0, stream>>>(h1b, rsg, clg, dvg, aggu);
        gemm_bf16<HG, true><<<dim3(G * 313, 4), 256, 0, stream>>>(aggu, W2t, b2, nullptr,
                nullptr, pooled + (size_t)t0 * HG);
    }
    pre0_kernel<<<8, 128, 0, stream>>>(pooled, Wih0, bih0, bhh0, pre0);
    lstm4<<<4, 256, 0, stream>>>(pre0, Whh0, Wih1, Whh1, bih1, bhh1, Wlin, blin,
                                 hbuf, hseq_g, flags, (float*)d_out);
}